// Round 1
// baseline (2208.331 us; speedup 1.0000x reference)
//
#include <hip/hip_runtime.h>

typedef unsigned short ushort_t;
typedef __attribute__((ext_vector_type(4))) float f32x4;
typedef __attribute__((ext_vector_type(8))) __bf16 bf16x8;
typedef __attribute__((ext_vector_type(4))) unsigned short ushort4_t;
typedef __attribute__((ext_vector_type(8))) unsigned short ushort8_t;

#define AS1 __attribute__((address_space(1)))
#define AS3 __attribute__((address_space(3)))

__device__ __forceinline__ float bf2f(ushort_t u) {
  unsigned int v = ((unsigned int)u) << 16;
  return __builtin_bit_cast(float, v);
}
__device__ __forceinline__ ushort_t f2bf(float f) {
  unsigned int u = __builtin_bit_cast(unsigned int, f);
  u += 0x7fffu + ((u >> 16) & 1u);
  return (ushort_t)(u >> 16);
}
__device__ __forceinline__ void storeC(float* p, float v) { *p = v; }
__device__ __forceinline__ void storeC(ushort_t* p, float v) { *p = f2bf(v); }

// ---------------------------------------------------------------- elementwise
__global__ __launch_bounds__(256) void cast_f32_bf16(const float* __restrict__ in,
                                                     ushort_t* __restrict__ outp) {
  size_t i = ((size_t)blockIdx.x * 256 + threadIdx.x) * 4;
  f32x4 v = *(const f32x4*)(const void*)&in[i];
  ushort4_t o;
#pragma unroll
  for (int j = 0; j < 4; ++j) o[j] = f2bf(v[j]);
  *(ushort4_t*)(void*)&outp[i] = o;
}

// W[K][N] f32 -> Wt[N][K] bf16
__global__ __launch_bounds__(256) void transpose_cast(const float* __restrict__ W,
                                                      ushort_t* __restrict__ Wt,
                                                      int K, int N) {
  __shared__ float tile[32][33];
  int n0 = blockIdx.x * 32, k0 = blockIdx.y * 32;
  int tx = threadIdx.x, ty = threadIdx.y;
#pragma unroll
  for (int i = 0; i < 4; ++i)
    tile[ty + 8 * i][tx] = W[(size_t)(k0 + ty + 8 * i) * N + n0 + tx];
  __syncthreads();
#pragma unroll
  for (int i = 0; i < 4; ++i)
    Wt[(size_t)(n0 + ty + 8 * i) * K + k0 + tx] = f2bf(tile[tx][ty + 8 * i]);
}

__global__ __launch_bounds__(256) void silu_mul(ushort_t* __restrict__ h1,
                                                const ushort_t* __restrict__ h3) {
  size_t i = ((size_t)blockIdx.x * 256 + threadIdx.x) * 8;
  ushort8_t a = *(const ushort8_t*)(const void*)&h1[i];
  ushort8_t b = *(const ushort8_t*)(const void*)&h3[i];
#pragma unroll
  for (int j = 0; j < 8; ++j) {
    float x = bf2f(a[j]);
    float g = x / (1.0f + __expf(-x));
    a[j] = f2bf(g * bf2f(b[j]));
  }
  *(ushort8_t*)(void*)&h1[i] = a;
}

// qb layout [b*2048+s][h*128+d], pairs (2i,2i+1)
__global__ __launch_bounds__(256) void rope_q(ushort_t* __restrict__ q,
                                              const float* __restrict__ fc,
                                              const float* __restrict__ fs) {
  int p = blockIdx.x * 256 + threadIdx.x;  // 0..4194303
  int i = p & 63;
  int h = (p >> 6) & 15;
  int row = p >> 10;       // b*2048+s
  int s = row & 2047;
  float c = fc[s * 64 + i], sn = fs[s * 64 + i];
  size_t idx = (size_t)row * 2048 + h * 128 + 2 * i;
  float xr = bf2f(q[idx]), xi = bf2f(q[idx + 1]);
  q[idx] = f2bf(xr * c - xi * sn);
  q[idx + 1] = f2bf(xr * sn + xi * c);
}

__global__ __launch_bounds__(256) void rope_k(ushort_t* __restrict__ k,
                                              float* __restrict__ okeys,
                                              const float* __restrict__ fc,
                                              const float* __restrict__ fs) {
  int p = blockIdx.x * 256 + threadIdx.x;  // 0..2097151
  int i = p & 63;
  int kh = (p >> 6) & 7;
  int row = p >> 9;        // b*2048+s
  int s = row & 2047;
  float c = fc[s * 64 + i], sn = fs[s * 64 + i];
  size_t idx = (size_t)row * 1024 + kh * 128 + 2 * i;
  float xr = bf2f(k[idx]), xi = bf2f(k[idx + 1]);
  float orr = xr * c - xi * sn;
  float oi = xr * sn + xi * c;
  k[idx] = f2bf(orr);
  k[idx + 1] = f2bf(oi);
  okeys[idx] = orr;
  okeys[idx + 1] = oi;
}

// vb[b*2048+s][kh*128+d] -> ovals f32 (same layout) and vbT[(b*8+kh)*128+d][s]
__global__ __launch_bounds__(256) void v_post(const ushort_t* __restrict__ vb,
                                              float* __restrict__ ovals,
                                              ushort_t* __restrict__ vbT) {
  __shared__ ushort_t tile[32][33];
  int s0 = blockIdx.x * 32, d0 = blockIdx.y * 32, bk = blockIdx.z;  // bk = b*8+kh
  int b = bk >> 3, kh = bk & 7;
  int tx = threadIdx.x, ty = threadIdx.y;
#pragma unroll
  for (int i = 0; i < 4; ++i) {
    int s = s0 + ty + 8 * i;
    size_t src = ((size_t)(b * 2048 + s)) * 1024 + kh * 128 + d0 + tx;
    ushort_t u = vb[src];
    tile[ty + 8 * i][tx] = u;
    ovals[src] = bf2f(u);
  }
  __syncthreads();
#pragma unroll
  for (int i = 0; i < 4; ++i) {
    int d = d0 + ty + 8 * i;
    vbT[((size_t)bk * 128 + d) * 2048 + s0 + tx] = tile[tx][ty + 8 * i];
  }
}

// ---------------------------------------------------------------- softmax
__device__ __forceinline__ float wave_max(float v) {
#pragma unroll
  for (int o = 32; o > 0; o >>= 1) v = fmaxf(v, __shfl_xor(v, o, 64));
  return v;
}
__device__ __forceinline__ float wave_sum(float v) {
#pragma unroll
  for (int o = 32; o > 0; o >>= 1) v += __shfl_xor(v, o, 64);
  return v;
}

// scores[z][q][k] f32 (4 heads per group), causal; P bf16 same layout
__global__ __launch_bounds__(256) void softmax_causal(const float* __restrict__ S,
                                                      ushort_t* __restrict__ P) {
  int q = blockIdx.x, z = blockIdx.y;
  const float* srow = S + ((size_t)z * 2048 + q) * 2048;
  ushort_t* prow = P + ((size_t)z * 2048 + q) * 2048;
  int t = threadIdx.x, w = t >> 6, lane = t & 63;
  int n = q + 1;
  __shared__ float redm[4];
  __shared__ float reds[4];
  float m = -1e30f;
  for (int k = t; k < n; k += 256) m = fmaxf(m, srow[k]);
  m = wave_max(m);
  if (lane == 0) redm[w] = m;
  __syncthreads();
  m = fmaxf(fmaxf(redm[0], redm[1]), fmaxf(redm[2], redm[3]));
  float sum = 0.0f;
  for (int k = t; k < n; k += 256) sum += __expf(srow[k] - m);
  sum = wave_sum(sum);
  if (lane == 0) reds[w] = sum;
  __syncthreads();
  sum = reds[0] + reds[1] + reds[2] + reds[3];
  float inv = 1.0f / sum;
  for (int k = t; k < 2048; k += 256) {
    float p = (k < n) ? __expf(srow[k] - m) * inv : 0.0f;
    prow[k] = f2bf(p);
  }
}

// ---------------------------------------------------------------- GEMM (NT)
// C[M][N] = alpha * A[M][K] @ Bt[N][K]^T, bf16 inputs, f32 accum.
// MODE 0: plain (z-strides). MODE 1: QK^T batched (g = head group).
// MODE 2: P@V batched.
template <int MODE, typename CT>
__global__ __launch_bounds__(256) void gemm_nt(
    const ushort_t* __restrict__ A, const ushort_t* __restrict__ B,
    CT* __restrict__ C, int M, int N, int K, int lda, int ldb, int ldc,
    long long strA, long long strB, long long strC, int g, float alpha) {
  __shared__ __align__(16) ushort_t sA[128 * 32];
  __shared__ __align__(16) ushort_t sB[128 * 32];
  const int r0 = blockIdx.y * 128;
  const int c0 = blockIdx.x * 128;
  const int bz = blockIdx.z;
  size_t offA = 0, offB = 0, offC = 0;
  int Keff = K;
  if constexpr (MODE == 0) {
    offA = (size_t)(strA * bz);
    offB = (size_t)(strB * bz);
    offC = (size_t)(strC * bz);
  } else {
    const int bh = g * 4 + bz;
    const int b = bh >> 4, h = bh & 15;
    if constexpr (MODE == 1) {
      if (c0 > r0) return;  // fully-masked block
      offA = ((size_t)(b * 2048)) * 2048 + h * 128;
      offB = ((size_t)(b * 2048)) * 1024 + (h >> 1) * 128;
      offC = ((size_t)bz) * 2048 * 2048;
    } else {
      offA = ((size_t)bz) * 2048 * 2048;
      offB = ((size_t)(b * 8 + (h >> 1))) * 128 * 2048;
      offC = ((size_t)(b * 2048)) * 2048 + h * 128;
      Keff = (r0 + 128 < K) ? (r0 + 128) : K;  // P[q][k]=0 for k>q
    }
  }
  const ushort_t* gA = A + offA;
  const ushort_t* gB = B + offB;
  const int t = threadIdx.x, w = t >> 6, lane = t & 63;
  const int sr = t >> 2;        // staging row within 64-row half
  const int sc = (t & 3) * 8;   // staging k-elem offset
  const int wr = (w >> 1) * 64, wc = (w & 1) * 64;
  const int fr = lane & 15, fk = (lane >> 4) * 8;
  f32x4 acc[4][4] = {};

  for (int k0 = 0; k0 < Keff; k0 += 32) {
#pragma unroll
    for (int i = 0; i < 2; ++i) {
      const int row = i * 64 + sr;
      __builtin_amdgcn_global_load_lds(
          (const AS1 void*)(gA + (size_t)(r0 + row) * lda + k0 + sc),
          (AS3 void*)((char*)sA + i * 4096 + w * 1024), 16, 0, 0);
      __builtin_amdgcn_global_load_lds(
          (const AS1 void*)(gB + (size_t)(c0 + row) * ldb + k0 + sc),
          (AS3 void*)((char*)sB + i * 4096 + w * 1024), 16, 0, 0);
    }
    __syncthreads();
    bf16x8 aF[4], bF[4];
#pragma unroll
    for (int m = 0; m < 4; ++m)
      aF[m] = *(const bf16x8*)(const void*)&sA[(wr + m * 16 + fr) * 32 + fk];
#pragma unroll
    for (int n = 0; n < 4; ++n)
      bF[n] = *(const bf16x8*)(const void*)&sB[(wc + n * 16 + fr) * 32 + fk];
#pragma unroll
    for (int m = 0; m < 4; ++m)
#pragma unroll
      for (int n = 0; n < 4; ++n)
        acc[m][n] = __builtin_amdgcn_mfma_f32_16x16x32_bf16(aF[m], bF[n],
                                                            acc[m][n], 0, 0, 0);
    __syncthreads();
  }

  CT* gC = C + offC;
  const int cr = r0 + wr + (lane >> 4) * 4;
  const int cc = c0 + wc + fr;
#pragma unroll
  for (int m = 0; m < 4; ++m)
#pragma unroll
    for (int n = 0; n < 4; ++n)
#pragma unroll
      for (int j = 0; j < 4; ++j)
        storeC(&gC[(size_t)(cr + m * 16 + j) * ldc + cc + n * 16],
               acc[m][n][j] * alpha);
}

// ---------------------------------------------------------------- host
extern "C" void kernel_launch(void* const* d_in, const int* in_sizes, int n_in,
                              void* d_out, int out_size, void* d_ws, size_t ws_size,
                              hipStream_t stream) {
  const float* x = (const float*)d_in[0];
  const float* wq = (const float*)d_in[1];
  const float* wk1 = (const float*)d_in[2];
  const float* wk2 = (const float*)d_in[3];
  const float* wk3 = (const float*)d_in[4];
  const float* wv1 = (const float*)d_in[5];
  const float* wv2 = (const float*)d_in[6];
  const float* wv3 = (const float*)d_in[7];
  const float* wo = (const float*)d_in[8];
  const float* fc = (const float*)d_in[9];
  const float* fs = (const float*)d_in[10];

  float* outp = (float*)d_out;               // [4096][2048]
  float* okeys = outp + 8388608;             // [4096][1024]
  float* ovals = outp + 12582912;            // [4096][1024]

  char* p = (char*)d_ws;
  auto alloc = [&](size_t bytes) {
    char* r = p;
    p += (bytes + 255) & ~(size_t)255;
    return r;
  };
  ushort_t* xb = (ushort_t*)alloc(4096ull * 2048 * 2);
  ushort_t* wqT = (ushort_t*)alloc(2048ull * 2048 * 2);
  ushort_t* wk1T = (ushort_t*)alloc(8192ull * 2048 * 2);
  ushort_t* wk2T = (ushort_t*)alloc(1024ull * 8192 * 2);
  ushort_t* wk3T = (ushort_t*)alloc(8192ull * 2048 * 2);
  ushort_t* wv1T = (ushort_t*)alloc(8192ull * 2048 * 2);
  ushort_t* wv2T = (ushort_t*)alloc(1024ull * 8192 * 2);
  ushort_t* wv3T = (ushort_t*)alloc(8192ull * 2048 * 2);
  ushort_t* woT = (ushort_t*)alloc(2048ull * 2048 * 2);
  ushort_t* qb = (ushort_t*)alloc(4096ull * 2048 * 2);
  ushort_t* kb = (ushort_t*)alloc(4096ull * 1024 * 2);
  ushort_t* vb = (ushort_t*)alloc(4096ull * 1024 * 2);
  ushort_t* vbT = (ushort_t*)alloc(4096ull * 1024 * 2);
  ushort_t* ob = (ushort_t*)alloc(4096ull * 2048 * 2);
  char* hreg = alloc(134217728ull);  // h1+h3, reused as scores+P
  ushort_t* h1 = (ushort_t*)hreg;
  ushort_t* h3 = (ushort_t*)(hreg + 67108864);
  float* scores = (float*)hreg;                      // 4*2048*2048 f32
  ushort_t* Pb = (ushort_t*)(hreg + 67108864);       // 4*2048*2048 bf16

  const float qk_scale = 0.08838834764831845f;  // 1/sqrt(128)
  dim3 tb(32, 8);

  // bf16 casts / weight transposes
  cast_f32_bf16<<<8192, 256, 0, stream>>>(x, xb);
  transpose_cast<<<dim3(64, 64), tb, 0, stream>>>(wq, wqT, 2048, 2048);
  transpose_cast<<<dim3(256, 64), tb, 0, stream>>>(wk1, wk1T, 2048, 8192);
  transpose_cast<<<dim3(32, 256), tb, 0, stream>>>(wk2, wk2T, 8192, 1024);
  transpose_cast<<<dim3(256, 64), tb, 0, stream>>>(wk3, wk3T, 2048, 8192);
  transpose_cast<<<dim3(256, 64), tb, 0, stream>>>(wv1, wv1T, 2048, 8192);
  transpose_cast<<<dim3(32, 256), tb, 0, stream>>>(wv2, wv2T, 8192, 1024);
  transpose_cast<<<dim3(256, 64), tb, 0, stream>>>(wv3, wv3T, 2048, 8192);
  transpose_cast<<<dim3(64, 64), tb, 0, stream>>>(wo, woT, 2048, 2048);

  // q projection + rope
  gemm_nt<0, ushort_t><<<dim3(16, 32, 1), 256, 0, stream>>>(
      xb, wqT, qb, 4096, 2048, 2048, 2048, 2048, 2048, 0, 0, 0, 0, 1.0f);
  rope_q<<<16384, 256, 0, stream>>>(qb, fc, fs);

  // k projection (SwiGLU) + rope + o_keys
  gemm_nt<0, ushort_t><<<dim3(64, 32, 1), 256, 0, stream>>>(
      xb, wk1T, h1, 4096, 8192, 2048, 2048, 2048, 8192, 0, 0, 0, 0, 1.0f);
  gemm_nt<0, ushort_t><<<dim3(64, 32, 1), 256, 0, stream>>>(
      xb, wk3T, h3, 4096, 8192, 2048, 2048, 2048, 8192, 0, 0, 0, 0, 1.0f);
  silu_mul<<<16384, 256, 0, stream>>>(h1, h3);
  gemm_nt<0, ushort_t><<<dim3(8, 32, 1), 256, 0, stream>>>(
      h1, wk2T, kb, 4096, 1024, 8192, 8192, 8192, 1024, 0, 0, 0, 0, 1.0f);
  rope_k<<<8192, 256, 0, stream>>>(kb, okeys, fc, fs);

  // v projection (SwiGLU) + o_values + transpose
  gemm_nt<0, ushort_t><<<dim3(64, 32, 1), 256, 0, stream>>>(
      xb, wv1T, h1, 4096, 8192, 2048, 2048, 2048, 8192, 0, 0, 0, 0, 1.0f);
  gemm_nt<0, ushort_t><<<dim3(64, 32, 1), 256, 0, stream>>>(
      xb, wv3T, h3, 4096, 8192, 2048, 2048, 2048, 8192, 0, 0, 0, 0, 1.0f);
  silu_mul<<<16384, 256, 0, stream>>>(h1, h3);
  gemm_nt<0, ushort_t><<<dim3(8, 32, 1), 256, 0, stream>>>(
      h1, wv2T, vb, 4096, 1024, 8192, 8192, 8192, 1024, 0, 0, 0, 0, 1.0f);
  v_post<<<dim3(64, 4, 16), tb, 0, stream>>>(vb, ovals, vbT);

  // attention: 8 groups x 4 heads (scores/P reuse the h1/h3 region)
  for (int gg = 0; gg < 8; ++gg) {
    gemm_nt<1, float><<<dim3(16, 16, 4), 256, 0, stream>>>(
        qb, kb, scores, 2048, 2048, 128, 2048, 1024, 2048, 0, 0, 0, gg, qk_scale);
    softmax_causal<<<dim3(2048, 4), 256, 0, stream>>>(scores, Pb);
    gemm_nt<2, ushort_t><<<dim3(1, 16, 4), 256, 0, stream>>>(
        Pb, vbT, ob, 2048, 128, 2048, 2048, 2048, 2048, 0, 0, 0, gg, 1.0f);
  }

  // output projection
  gemm_nt<0, float><<<dim3(16, 32, 1), 256, 0, stream>>>(
      ob, woT, outp, 4096, 2048, 2048, 2048, 2048, 2048, 0, 0, 0, 0, 1.0f);

  (void)in_sizes; (void)n_in; (void)out_size; (void)ws_size;
}

// Round 2
// 1970.255 us; speedup vs baseline: 1.1208x; 1.1208x over previous
//
#include <hip/hip_runtime.h>

typedef unsigned short ushort_t;
typedef __attribute__((ext_vector_type(4))) float f32x4;
typedef __attribute__((ext_vector_type(8))) __bf16 bf16x8;
typedef __attribute__((ext_vector_type(4))) unsigned short ushort4_t;
typedef __attribute__((ext_vector_type(8))) unsigned short ushort8_t;

#define AS1 __attribute__((address_space(1)))
#define AS3 __attribute__((address_space(3)))

__device__ __forceinline__ float bf2f(ushort_t u) {
  unsigned int v = ((unsigned int)u) << 16;
  return __builtin_bit_cast(float, v);
}
__device__ __forceinline__ ushort_t f2bf(float f) {
  unsigned int u = __builtin_bit_cast(unsigned int, f);
  u += 0x7fffu + ((u >> 16) & 1u);
  return (ushort_t)(u >> 16);
}
__device__ __forceinline__ void storeC(float* p, float v) { *p = v; }
__device__ __forceinline__ void storeC(ushort_t* p, float v) { *p = f2bf(v); }

// ---------------------------------------------------------------- elementwise
__global__ __launch_bounds__(256) void cast_f32_bf16(const float* __restrict__ in,
                                                     ushort_t* __restrict__ outp) {
  size_t i = ((size_t)blockIdx.x * 256 + threadIdx.x) * 4;
  f32x4 v = *(const f32x4*)(const void*)&in[i];
  ushort4_t o;
#pragma unroll
  for (int j = 0; j < 4; ++j) o[j] = f2bf(v[j]);
  *(ushort4_t*)(void*)&outp[i] = o;
}

// W[K][N] f32 -> Wt[N][K] bf16
__global__ __launch_bounds__(256) void transpose_cast(const float* __restrict__ W,
                                                      ushort_t* __restrict__ Wt,
                                                      int K, int N) {
  __shared__ float tile[32][33];
  int n0 = blockIdx.x * 32, k0 = blockIdx.y * 32;
  int tx = threadIdx.x, ty = threadIdx.y;
#pragma unroll
  for (int i = 0; i < 4; ++i)
    tile[ty + 8 * i][tx] = W[(size_t)(k0 + ty + 8 * i) * N + n0 + tx];
  __syncthreads();
#pragma unroll
  for (int i = 0; i < 4; ++i)
    Wt[(size_t)(n0 + ty + 8 * i) * K + k0 + tx] = f2bf(tile[tx][ty + 8 * i]);
}

__global__ __launch_bounds__(256) void silu_mul(ushort_t* __restrict__ h1,
                                                const ushort_t* __restrict__ h3) {
  size_t i = ((size_t)blockIdx.x * 256 + threadIdx.x) * 8;
  ushort8_t a = *(const ushort8_t*)(const void*)&h1[i];
  ushort8_t b = *(const ushort8_t*)(const void*)&h3[i];
#pragma unroll
  for (int j = 0; j < 8; ++j) {
    float x = bf2f(a[j]);
    float g = x / (1.0f + __expf(-x));
    a[j] = f2bf(g * bf2f(b[j]));
  }
  *(ushort8_t*)(void*)&h1[i] = a;
}

__global__ __launch_bounds__(256) void rope_q(ushort_t* __restrict__ q,
                                              const float* __restrict__ fc,
                                              const float* __restrict__ fs) {
  int p = blockIdx.x * 256 + threadIdx.x;
  int i = p & 63;
  int h = (p >> 6) & 15;
  int row = p >> 10;
  int s = row & 2047;
  float c = fc[s * 64 + i], sn = fs[s * 64 + i];
  size_t idx = (size_t)row * 2048 + h * 128 + 2 * i;
  float xr = bf2f(q[idx]), xi = bf2f(q[idx + 1]);
  q[idx] = f2bf(xr * c - xi * sn);
  q[idx + 1] = f2bf(xr * sn + xi * c);
}

__global__ __launch_bounds__(256) void rope_k(ushort_t* __restrict__ k,
                                              float* __restrict__ okeys,
                                              const float* __restrict__ fc,
                                              const float* __restrict__ fs) {
  int p = blockIdx.x * 256 + threadIdx.x;
  int i = p & 63;
  int kh = (p >> 6) & 7;
  int row = p >> 9;
  int s = row & 2047;
  float c = fc[s * 64 + i], sn = fs[s * 64 + i];
  size_t idx = (size_t)row * 1024 + kh * 128 + 2 * i;
  float xr = bf2f(k[idx]), xi = bf2f(k[idx + 1]);
  float orr = xr * c - xi * sn;
  float oi = xr * sn + xi * c;
  k[idx] = f2bf(orr);
  k[idx + 1] = f2bf(oi);
  okeys[idx] = orr;
  okeys[idx + 1] = oi;
}

__global__ __launch_bounds__(256) void v_post(const ushort_t* __restrict__ vb,
                                              float* __restrict__ ovals,
                                              ushort_t* __restrict__ vbT) {
  __shared__ ushort_t tile[32][33];
  int s0 = blockIdx.x * 32, d0 = blockIdx.y * 32, bk = blockIdx.z;
  int b = bk >> 3, kh = bk & 7;
  int tx = threadIdx.x, ty = threadIdx.y;
#pragma unroll
  for (int i = 0; i < 4; ++i) {
    int s = s0 + ty + 8 * i;
    size_t src = ((size_t)(b * 2048 + s)) * 1024 + kh * 128 + d0 + tx;
    ushort_t u = vb[src];
    tile[ty + 8 * i][tx] = u;
    ovals[src] = bf2f(u);
  }
  __syncthreads();
#pragma unroll
  for (int i = 0; i < 4; ++i) {
    int d = d0 + ty + 8 * i;
    vbT[((size_t)bk * 128 + d) * 2048 + s0 + tx] = tile[tx][ty + 8 * i];
  }
}

// ---------------------------------------------------------------- softmax
__device__ __forceinline__ float wave_max(float v) {
#pragma unroll
  for (int o = 32; o > 0; o >>= 1) v = fmaxf(v, __shfl_xor(v, o, 64));
  return v;
}
__device__ __forceinline__ float wave_sum(float v) {
#pragma unroll
  for (int o = 32; o > 0; o >>= 1) v += __shfl_xor(v, o, 64);
  return v;
}

__global__ __launch_bounds__(256) void softmax_causal(const float* __restrict__ S,
                                                      ushort_t* __restrict__ P) {
  int q = blockIdx.x, z = blockIdx.y;
  const float* srow = S + ((size_t)z * 2048 + q) * 2048;
  ushort_t* prow = P + ((size_t)z * 2048 + q) * 2048;
  int t = threadIdx.x, w = t >> 6, lane = t & 63;
  int n = q + 1;
  __shared__ float redm[4];
  __shared__ float reds[4];
  float m = -1e30f;
  for (int k = t; k < n; k += 256) m = fmaxf(m, srow[k]);
  m = wave_max(m);
  if (lane == 0) redm[w] = m;
  __syncthreads();
  m = fmaxf(fmaxf(redm[0], redm[1]), fmaxf(redm[2], redm[3]));
  float sum = 0.0f;
  for (int k = t; k < n; k += 256) sum += __expf(srow[k] - m);
  sum = wave_sum(sum);
  if (lane == 0) reds[w] = sum;
  __syncthreads();
  sum = reds[0] + reds[1] + reds[2] + reds[3];
  float inv = 1.0f / sum;
  for (int k = t; k < 2048; k += 256) {
    float p = (k < n) ? __expf(srow[k] - m) * inv : 0.0f;
    prow[k] = f2bf(p);
  }
}

// ------------------------------------------------- 128^2 GEMM (attn + N=1024)
template <int MODE, typename CT>
__global__ __launch_bounds__(256) void gemm_nt(
    const ushort_t* __restrict__ A, const ushort_t* __restrict__ B,
    CT* __restrict__ C, int M, int N, int K, int lda, int ldb, int ldc,
    long long strA, long long strB, long long strC, int g, float alpha) {
  __shared__ __align__(16) ushort_t sA[128 * 32];
  __shared__ __align__(16) ushort_t sB[128 * 32];
  const int r0 = blockIdx.y * 128;
  const int c0 = blockIdx.x * 128;
  const int bz = blockIdx.z;
  size_t offA = 0, offB = 0, offC = 0;
  int Keff = K;
  if constexpr (MODE == 0) {
    offA = (size_t)(strA * bz);
    offB = (size_t)(strB * bz);
    offC = (size_t)(strC * bz);
  } else {
    const int bh = g * 4 + bz;
    const int b = bh >> 4, h = bh & 15;
    if constexpr (MODE == 1) {
      if (c0 > r0) return;
      offA = ((size_t)(b * 2048)) * 2048 + h * 128;
      offB = ((size_t)(b * 2048)) * 1024 + (h >> 1) * 128;
      offC = ((size_t)bz) * 2048 * 2048;
    } else {
      offA = ((size_t)bz) * 2048 * 2048;
      offB = ((size_t)(b * 8 + (h >> 1))) * 128 * 2048;
      offC = ((size_t)(b * 2048)) * 2048 + h * 128;
      Keff = (r0 + 128 < K) ? (r0 + 128) : K;
    }
  }
  const ushort_t* gA = A + offA;
  const ushort_t* gB = B + offB;
  const int t = threadIdx.x, w = t >> 6, lane = t & 63;
  const int sr = t >> 2;
  const int sc = (t & 3) * 8;
  const int wr = (w >> 1) * 64, wc = (w & 1) * 64;
  const int fr = lane & 15, fk = (lane >> 4) * 8;
  f32x4 acc[4][4] = {};

  for (int k0 = 0; k0 < Keff; k0 += 32) {
#pragma unroll
    for (int i = 0; i < 2; ++i) {
      const int row = i * 64 + sr;
      __builtin_amdgcn_global_load_lds(
          (const AS1 void*)(gA + (size_t)(r0 + row) * lda + k0 + sc),
          (AS3 void*)((char*)sA + i * 4096 + w * 1024), 16, 0, 0);
      __builtin_amdgcn_global_load_lds(
          (const AS1 void*)(gB + (size_t)(c0 + row) * ldb + k0 + sc),
          (AS3 void*)((char*)sB + i * 4096 + w * 1024), 16, 0, 0);
    }
    __syncthreads();
    bf16x8 aF[4], bF[4];
#pragma unroll
    for (int m = 0; m < 4; ++m)
      aF[m] = *(const bf16x8*)(const void*)&sA[(wr + m * 16 + fr) * 32 + fk];
#pragma unroll
    for (int n = 0; n < 4; ++n)
      bF[n] = *(const bf16x8*)(const void*)&sB[(wc + n * 16 + fr) * 32 + fk];
#pragma unroll
    for (int m = 0; m < 4; ++m)
#pragma unroll
      for (int n = 0; n < 4; ++n)
        acc[m][n] = __builtin_amdgcn_mfma_f32_16x16x32_bf16(aF[m], bF[n],
                                                            acc[m][n], 0, 0, 0);
    __syncthreads();
  }

  CT* gC = C + offC;
  const int cr = r0 + wr + (lane >> 4) * 4;
  const int cc = c0 + wc + fr;
#pragma unroll
  for (int m = 0; m < 4; ++m)
#pragma unroll
    for (int n = 0; n < 4; ++n)
#pragma unroll
      for (int j = 0; j < 4; ++j)
        storeC(&gC[(size_t)(cr + m * 16 + j) * ldc + cc + n * 16],
               acc[m][n][j] * alpha);
}

// ------------------------------------------- 256^2 8-phase GEMM (T1..T5)
// C[M][N] = A[M][K] @ B[N][K]^T, bf16 in, f32 accum. 512 thr = 8 waves (2Mx4N).
// LDS 128KB: 2 buffers x (A 256x64 + B 256x64) bf16, XOR-swizzled slots.
template <typename CT>
__global__ __launch_bounds__(512, 2) void gemm256(
    const ushort_t* __restrict__ A, const ushort_t* __restrict__ B,
    CT* __restrict__ C, int K, int lda, int ldb, int ldc,
    int nwgx, int nwg, long long strA, long long strB, long long strC) {
  __shared__ __align__(16) char smem[131072];
  const int bz = blockIdx.y;
  const int bid = blockIdx.x;
  const int swz = (bid & 7) * (nwg >> 3) + (bid >> 3);  // bijective: nwg%8==0
  const int r0 = (swz / nwgx) * 256;
  const int c0 = (swz % nwgx) * 256;
  const int t = threadIdx.x, w = t >> 6, lane = t & 63;
  const int wm = w >> 2, wn = w & 3;
  const int fr = lane & 15, fh = lane >> 4;
  const int sl0 = (fh ^ (fr & 7)) << 4;   // swizzled 16B slot, kstep0
  const int ldsw = w * 1024;
  const int srow = t >> 3;                 // staging row in 64-row chunk
  const int scb = (t & 7) ^ (srow & 7);    // inverse-swizzled global colblock
  const int NT = K >> 6;
  const ushort_t* gA = A + strA * bz + (size_t)(r0 + srow) * lda + scb * 8;
  const ushort_t* gB = B + strB * bz + (size_t)(c0 + srow) * ldb + scb * 8;

  auto stage = [&](int tile, int isB, int h) {
    const ushort_t* g = isB ? gB : gA;
    const size_t ld = isB ? (size_t)ldb : (size_t)lda;
    char* lp = (char*)smem + ((tile & 1) << 16) + (isB ? 32768 : 0) + (h << 14) + ldsw;
    const ushort_t* src = g + (size_t)(h * 128) * ld + tile * 64;
    __builtin_amdgcn_global_load_lds((const AS1 void*)src, (AS3 void*)lp, 16, 0, 0);
    __builtin_amdgcn_global_load_lds((const AS1 void*)(src + 64 * ld),
                                     (AS3 void*)(lp + 8192), 16, 0, 0);
  };

  f32x4 acc[8][4] = {};

  // prologue: tile0 (A+B) -> buf0, tile1 A -> buf1; wait first 8 loads
  stage(0, 0, 0); stage(0, 0, 1); stage(0, 1, 0); stage(0, 1, 1);
  if (NT > 1) {
    stage(1, 0, 0); stage(1, 0, 1);
    asm volatile("s_waitcnt vmcnt(4)" ::: "memory");
  } else {
    asm volatile("s_waitcnt vmcnt(0)" ::: "memory");
  }
  __builtin_amdgcn_sched_barrier(0);
  __builtin_amdgcn_s_barrier();

  const int aOff = wm * 16384 + fr * 128;
  const int bOff = 32768 + wn * 8192 + fr * 128;

  for (int kt = 0; kt < NT; ++kt) {
    const int buf = (kt & 1) << 16;
    const char* la = (const char*)smem + buf + aOff;
    const char* lb = (const char*)smem + buf + bOff;
    bf16x8 aF0[8], aF1[8], bF0[4], bF1[4];
    // ---- phase 1: read k0 frags; stage B(kt+1) h0; MFMA k0 m0-3
#pragma unroll
    for (int m = 0; m < 8; ++m)
      aF0[m] = *(const bf16x8*)(const void*)(la + m * 2048 + sl0);
#pragma unroll
    for (int n = 0; n < 4; ++n)
      bF0[n] = *(const bf16x8*)(const void*)(lb + n * 2048 + sl0);
    if (kt + 1 < NT) stage(kt + 1, 1, 0);
    __builtin_amdgcn_s_barrier();
    asm volatile("s_waitcnt lgkmcnt(0)" ::: "memory");
    __builtin_amdgcn_sched_barrier(0);
    __builtin_amdgcn_s_setprio(1);
#pragma unroll
    for (int m = 0; m < 4; ++m)
#pragma unroll
      for (int n = 0; n < 4; ++n)
        acc[m][n] = __builtin_amdgcn_mfma_f32_16x16x32_bf16(aF0[m], bF0[n], acc[m][n], 0, 0, 0);
    __builtin_amdgcn_s_setprio(0);
    __builtin_amdgcn_s_barrier();
    // ---- phase 2: read k1 frags; stage B(kt+1) h1; MFMA k0 m4-7
#pragma unroll
    for (int m = 0; m < 8; ++m)
      aF1[m] = *(const bf16x8*)(const void*)(la + m * 2048 + (sl0 ^ 64));
#pragma unroll
    for (int n = 0; n < 4; ++n)
      bF1[n] = *(const bf16x8*)(const void*)(lb + n * 2048 + (sl0 ^ 64));
    if (kt + 1 < NT) stage(kt + 1, 1, 1);
    __builtin_amdgcn_s_barrier();
    asm volatile("s_waitcnt lgkmcnt(0)" ::: "memory");
    __builtin_amdgcn_sched_barrier(0);
    __builtin_amdgcn_s_setprio(1);
#pragma unroll
    for (int m = 4; m < 8; ++m)
#pragma unroll
      for (int n = 0; n < 4; ++n)
        acc[m][n] = __builtin_amdgcn_mfma_f32_16x16x32_bf16(aF0[m], bF0[n], acc[m][n], 0, 0, 0);
    __builtin_amdgcn_s_setprio(0);
    __builtin_amdgcn_s_barrier();
    // ---- phase 3: stage A(kt+2) h0 (A-reads all done by ph2 fence); MFMA k1 m0-3
    if (kt + 2 < NT) stage(kt + 2, 0, 0);
    __builtin_amdgcn_s_barrier();
    __builtin_amdgcn_s_setprio(1);
#pragma unroll
    for (int m = 0; m < 4; ++m)
#pragma unroll
      for (int n = 0; n < 4; ++n)
        acc[m][n] = __builtin_amdgcn_mfma_f32_16x16x32_bf16(aF1[m], bF1[n], acc[m][n], 0, 0, 0);
    __builtin_amdgcn_s_setprio(0);
    __builtin_amdgcn_s_barrier();
    // ---- phase 4: stage A(kt+2) h1; MFMA k1 m4-7; counted vmcnt; barrier
    if (kt + 2 < NT) stage(kt + 2, 0, 1);
    __builtin_amdgcn_s_setprio(1);
#pragma unroll
    for (int m = 4; m < 8; ++m)
#pragma unroll
      for (int n = 0; n < 4; ++n)
        acc[m][n] = __builtin_amdgcn_mfma_f32_16x16x32_bf16(aF1[m], bF1[n], acc[m][n], 0, 0, 0);
    __builtin_amdgcn_s_setprio(0);
    if (kt + 2 < NT)
      asm volatile("s_waitcnt vmcnt(4)" ::: "memory");
    else if (kt + 1 < NT)
      asm volatile("s_waitcnt vmcnt(0)" ::: "memory");
    __builtin_amdgcn_sched_barrier(0);
    __builtin_amdgcn_s_barrier();
  }

  CT* gC = C + strC * bz;
  const int cr = r0 + wm * 128 + fh * 4;
  const int cc = c0 + wn * 64 + fr;
#pragma unroll
  for (int m = 0; m < 8; ++m)
#pragma unroll
    for (int n = 0; n < 4; ++n)
#pragma unroll
      for (int j = 0; j < 4; ++j)
        storeC(&gC[(size_t)(cr + m * 16 + j) * ldc + cc + n * 16], acc[m][n][j]);
}

// ---------------------------------------------------------------- host
extern "C" void kernel_launch(void* const* d_in, const int* in_sizes, int n_in,
                              void* d_out, int out_size, void* d_ws, size_t ws_size,
                              hipStream_t stream) {
  const float* x = (const float*)d_in[0];
  const float* wq = (const float*)d_in[1];
  const float* wk1 = (const float*)d_in[2];
  const float* wk2 = (const float*)d_in[3];
  const float* wk3 = (const float*)d_in[4];
  const float* wv1 = (const float*)d_in[5];
  const float* wv2 = (const float*)d_in[6];
  const float* wv3 = (const float*)d_in[7];
  const float* wo = (const float*)d_in[8];
  const float* fc = (const float*)d_in[9];
  const float* fs = (const float*)d_in[10];

  float* outp = (float*)d_out;
  float* okeys = outp + 8388608;
  float* ovals = outp + 12582912;

  char* p = (char*)d_ws;
  auto alloc = [&](size_t bytes) {
    char* r = p;
    p += (bytes + 255) & ~(size_t)255;
    return r;
  };
  ushort_t* xb = (ushort_t*)alloc(4096ull * 2048 * 2);
  ushort_t* wqT = (ushort_t*)alloc(2048ull * 2048 * 2);
  ushort_t* wk1T = (ushort_t*)alloc(8192ull * 2048 * 2);  // adjacent:
  ushort_t* wk3T = (ushort_t*)alloc(8192ull * 2048 * 2);  // wk3T = wk1T+16777216
  ushort_t* wk2T = (ushort_t*)alloc(1024ull * 8192 * 2);
  ushort_t* wv1T = (ushort_t*)alloc(8192ull * 2048 * 2);  // adjacent:
  ushort_t* wv3T = (ushort_t*)alloc(8192ull * 2048 * 2);  // wv3T = wv1T+16777216
  ushort_t* wv2T = (ushort_t*)alloc(1024ull * 8192 * 2);
  ushort_t* woT = (ushort_t*)alloc(2048ull * 2048 * 2);
  ushort_t* qb = (ushort_t*)alloc(4096ull * 2048 * 2);
  ushort_t* kb = (ushort_t*)alloc(4096ull * 1024 * 2);
  ushort_t* vb = (ushort_t*)alloc(4096ull * 1024 * 2);
  ushort_t* vbT = (ushort_t*)alloc(4096ull * 1024 * 2);
  ushort_t* ob = (ushort_t*)alloc(4096ull * 2048 * 2);
  char* hreg = alloc(134217728ull);
  ushort_t* h1 = (ushort_t*)hreg;
  ushort_t* h3 = (ushort_t*)(hreg + 67108864);
  float* scores = (float*)hreg;
  ushort_t* Pb = (ushort_t*)(hreg + 67108864);

  const float qk_scale = 0.08838834764831845f;
  dim3 tb(32, 8);

  cast_f32_bf16<<<8192, 256, 0, stream>>>(x, xb);
  transpose_cast<<<dim3(64, 64), tb, 0, stream>>>(wq, wqT, 2048, 2048);
  transpose_cast<<<dim3(256, 64), tb, 0, stream>>>(wk1, wk1T, 2048, 8192);
  transpose_cast<<<dim3(32, 256), tb, 0, stream>>>(wk2, wk2T, 8192, 1024);
  transpose_cast<<<dim3(256, 64), tb, 0, stream>>>(wk3, wk3T, 2048, 8192);
  transpose_cast<<<dim3(256, 64), tb, 0, stream>>>(wv1, wv1T, 2048, 8192);
  transpose_cast<<<dim3(32, 256), tb, 0, stream>>>(wv2, wv2T, 8192, 1024);
  transpose_cast<<<dim3(256, 64), tb, 0, stream>>>(wv3, wv3T, 2048, 8192);
  transpose_cast<<<dim3(64, 64), tb, 0, stream>>>(wo, woT, 2048, 2048);

  // q projection + rope  (M=4096,N=2048,K=2048)
  gemm256<ushort_t><<<dim3(128, 1), 512, 0, stream>>>(
      xb, wqT, qb, 2048, 2048, 2048, 2048, 8, 128, 0, 0, 0);
  rope_q<<<16384, 256, 0, stream>>>(qb, fc, fs);

  // k gates: h1 = x@wk1, h3 = x@wk3 batched (M=4096,N=8192,K=2048)
  gemm256<ushort_t><<<dim3(512, 2), 512, 0, stream>>>(
      xb, wk1T, h1, 2048, 2048, 2048, 8192, 32, 512, 0, 16777216, 33554432);
  silu_mul<<<16384, 256, 0, stream>>>(h1, h3);
  gemm_nt<0, ushort_t><<<dim3(8, 32, 1), 256, 0, stream>>>(
      h1, wk2T, kb, 4096, 1024, 8192, 8192, 8192, 1024, 0, 0, 0, 0, 1.0f);
  rope_k<<<8192, 256, 0, stream>>>(kb, okeys, fc, fs);

  // v gates
  gemm256<ushort_t><<<dim3(512, 2), 512, 0, stream>>>(
      xb, wv1T, h1, 2048, 2048, 2048, 8192, 32, 512, 0, 16777216, 33554432);
  silu_mul<<<16384, 256, 0, stream>>>(h1, h3);
  gemm_nt<0, ushort_t><<<dim3(8, 32, 1), 256, 0, stream>>>(
      h1, wv2T, vb, 4096, 1024, 8192, 8192, 8192, 1024, 0, 0, 0, 0, 1.0f);
  v_post<<<dim3(64, 4, 16), tb, 0, stream>>>(vb, ovals, vbT);

  // attention: 8 groups x 4 heads
  for (int gg = 0; gg < 8; ++gg) {
    gemm_nt<1, float><<<dim3(16, 16, 4), 256, 0, stream>>>(
        qb, kb, scores, 2048, 2048, 128, 2048, 1024, 2048, 0, 0, 0, gg, qk_scale);
    softmax_causal<<<dim3(2048, 4), 256, 0, stream>>>(scores, Pb);
    gemm_nt<2, ushort_t><<<dim3(1, 16, 4), 256, 0, stream>>>(
        Pb, vbT, ob, 2048, 128, 2048, 2048, 2048, 2048, 0, 0, 0, gg, 1.0f);
  }

  // output projection (M=4096,N=2048,K=2048)
  gemm256<float><<<dim3(128, 1), 512, 0, stream>>>(
      ob, woT, outp, 2048, 2048, 2048, 2048, 8, 128, 0, 0, 0);

  (void)in_sizes; (void)n_in; (void)out_size; (void)ws_size;
}

// Round 3
// 1365.299 us; speedup vs baseline: 1.6175x; 1.4431x over previous
//
#include <hip/hip_runtime.h>

typedef unsigned short ushort_t;
typedef __attribute__((ext_vector_type(4))) float f32x4;
typedef __attribute__((ext_vector_type(8))) __bf16 bf16x8;
typedef __attribute__((ext_vector_type(4))) unsigned short ushort4_t;
typedef __attribute__((ext_vector_type(8))) unsigned short ushort8_t;
typedef __attribute__((ext_vector_type(2))) unsigned int u32x2;

#define AS1 __attribute__((address_space(1)))
#define AS3 __attribute__((address_space(3)))

__device__ __forceinline__ float bf2f(ushort_t u) {
  unsigned int v = ((unsigned int)u) << 16;
  return __builtin_bit_cast(float, v);
}
__device__ __forceinline__ ushort_t f2bf(float f) {
  unsigned int u = __builtin_bit_cast(unsigned int, f);
  u += 0x7fffu + ((u >> 16) & 1u);
  return (ushort_t)(u >> 16);
}
__device__ __forceinline__ void storeC(float* p, float v) { *p = v; }
__device__ __forceinline__ void storeC(ushort_t* p, float v) { *p = f2bf(v); }

// ---------------------------------------------------------------- elementwise
__global__ __launch_bounds__(256) void cast_f32_bf16(const float* __restrict__ in,
                                                     ushort_t* __restrict__ outp) {
  size_t i = ((size_t)blockIdx.x * 256 + threadIdx.x) * 4;
  f32x4 v = *(const f32x4*)(const void*)&in[i];
  ushort4_t o;
#pragma unroll
  for (int j = 0; j < 4; ++j) o[j] = f2bf(v[j]);
  *(ushort4_t*)(void*)&outp[i] = o;
}

// W[K][N] f32 -> Wt[N][K] bf16
__global__ __launch_bounds__(256) void transpose_cast(const float* __restrict__ W,
                                                      ushort_t* __restrict__ Wt,
                                                      int K, int N) {
  __shared__ float tile[32][33];
  int n0 = blockIdx.x * 32, k0 = blockIdx.y * 32;
  int tx = threadIdx.x, ty = threadIdx.y;
#pragma unroll
  for (int i = 0; i < 4; ++i)
    tile[ty + 8 * i][tx] = W[(size_t)(k0 + ty + 8 * i) * N + n0 + tx];
  __syncthreads();
#pragma unroll
  for (int i = 0; i < 4; ++i)
    Wt[(size_t)(n0 + ty + 8 * i) * K + k0 + tx] = f2bf(tile[tx][ty + 8 * i]);
}

__global__ __launch_bounds__(256) void silu_mul(ushort_t* __restrict__ h1,
                                                const ushort_t* __restrict__ h3) {
  size_t i = ((size_t)blockIdx.x * 256 + threadIdx.x) * 8;
  ushort8_t a = *(const ushort8_t*)(const void*)&h1[i];
  ushort8_t b = *(const ushort8_t*)(const void*)&h3[i];
#pragma unroll
  for (int j = 0; j < 8; ++j) {
    float x = bf2f(a[j]);
    float g = x / (1.0f + __expf(-x));
    a[j] = f2bf(g * bf2f(b[j]));
  }
  *(ushort8_t*)(void*)&h1[i] = a;
}

// qb layout [b*2048+s][h*128+d]; qk_scale folded in here (q only feeds attn)
__global__ __launch_bounds__(256) void rope_q(ushort_t* __restrict__ q,
                                              const float* __restrict__ fc,
                                              const float* __restrict__ fs) {
  const float alpha = 0.08838834764831845f;  // 1/sqrt(128)
  int p = blockIdx.x * 256 + threadIdx.x;
  int i = p & 63;
  int h = (p >> 6) & 15;
  int row = p >> 10;
  int s = row & 2047;
  float c = fc[s * 64 + i] * alpha, sn = fs[s * 64 + i] * alpha;
  size_t idx = (size_t)row * 2048 + h * 128 + 2 * i;
  float xr = bf2f(q[idx]), xi = bf2f(q[idx + 1]);
  q[idx] = f2bf(xr * c - xi * sn);
  q[idx + 1] = f2bf(xr * sn + xi * c);
}

__global__ __launch_bounds__(256) void rope_k(ushort_t* __restrict__ k,
                                              float* __restrict__ okeys,
                                              const float* __restrict__ fc,
                                              const float* __restrict__ fs) {
  int p = blockIdx.x * 256 + threadIdx.x;
  int i = p & 63;
  int kh = (p >> 6) & 7;
  int row = p >> 9;
  int s = row & 2047;
  float c = fc[s * 64 + i], sn = fs[s * 64 + i];
  size_t idx = (size_t)row * 1024 + kh * 128 + 2 * i;
  float xr = bf2f(k[idx]), xi = bf2f(k[idx + 1]);
  float orr = xr * c - xi * sn;
  float oi = xr * sn + xi * c;
  k[idx] = f2bf(orr);
  k[idx + 1] = f2bf(oi);
  okeys[idx] = orr;
  okeys[idx + 1] = oi;
}

__global__ __launch_bounds__(256) void v_post(const ushort_t* __restrict__ vb,
                                              float* __restrict__ ovals,
                                              ushort_t* __restrict__ vbT) {
  __shared__ ushort_t tile[32][33];
  int s0 = blockIdx.x * 32, d0 = blockIdx.y * 32, bk = blockIdx.z;
  int b = bk >> 3, kh = bk & 7;
  int tx = threadIdx.x, ty = threadIdx.y;
#pragma unroll
  for (int i = 0; i < 4; ++i) {
    int s = s0 + ty + 8 * i;
    size_t src = ((size_t)(b * 2048 + s)) * 1024 + kh * 128 + d0 + tx;
    ushort_t u = vb[src];
    tile[ty + 8 * i][tx] = u;
    ovals[src] = bf2f(u);
  }
  __syncthreads();
#pragma unroll
  for (int i = 0; i < 4; ++i) {
    int d = d0 + ty + 8 * i;
    vbT[((size_t)bk * 128 + d) * 2048 + s0 + tx] = tile[tx][ty + 8 * i];
  }
}

// ---------------------------------------------------------------- flash attn
// 256 blocks = (pair 8) x (bh 32); block processes q-tiles qi=x and 15-x
// (perfect balance: 34 kv-tiles each). 4 waves x 32 q-rows; KVBLK=64.
// Swapped QK^T (S^T = mfma(K,Q)); online softmax lane-local per q-column;
// P via cvt_pk -> wave-private LDS -> B-frags; O^T accumulated in regs.
__global__ __launch_bounds__(256) void flash_attn(
    const ushort_t* __restrict__ Q, const ushort_t* __restrict__ Kg,
    const ushort_t* __restrict__ VT, ushort_t* __restrict__ O) {
  __shared__ __align__(16) char smem[81920];  // K dbuf 32K | V dbuf 32K | P 16K
  const int xp = blockIdx.x;
  const int bh = blockIdx.y;
  const int b = bh >> 4, h = bh & 15, kh = h >> 1;
  const int t = threadIdx.x, w = t >> 6, lane = t & 63;
  const int fr = lane & 15, fh = lane >> 4;
  const size_t kelem0 = ((size_t)b * 2048) * 1024 + kh * 128;
  const size_t velem0 = ((size_t)(b * 8 + kh)) * 128 * 2048;
  const size_t qrow0 = (size_t)b * 2048;

  // per-lane staging source offsets (XOR-pre-swizzled so LDS stays linear)
  size_t oK[4], oV[4];
#pragma unroll
  for (int qv = 0; qv < 4; ++qv) {
    int row = w * 16 + qv * 4 + (lane >> 4);          // kv row 0..63
    oK[qv] = (size_t)row * 1024 + (((lane & 15) ^ (row & 7)) * 8);
    int rd = w * 32 + qv * 8 + (lane >> 3);           // d row 0..127
    oV[qv] = (size_t)rd * 2048 + (((lane & 7) ^ (rd & 7)) * 8);
  }

  auto stage = [&](int tile, int buf) {
    const size_t kc = (size_t)tile * 64 * 1024;
    const int vc = tile * 64;
    char* kd = smem + buf * 16384 + w * 4096;
    char* vd = smem + 32768 + buf * 16384 + w * 4096;
#pragma unroll
    for (int qv = 0; qv < 4; ++qv) {
      __builtin_amdgcn_global_load_lds((const AS1 void*)(Kg + kelem0 + kc + oK[qv]),
                                       (AS3 void*)(kd + qv * 1024), 16, 0, 0);
      __builtin_amdgcn_global_load_lds((const AS1 void*)(VT + velem0 + oV[qv] + vc),
                                       (AS3 void*)(vd + qv * 1024), 16, 0, 0);
    }
  };

#pragma unroll 1
  for (int ph = 0; ph < 2; ++ph) {
    const int qi = ph ? (15 - xp) : xp;
    const int qbase = qi * 128;
    const int qw = qbase + w * 32;
    const int nt = 2 * qi + 2;

    bf16x8 qF[2][4];
#pragma unroll
    for (int qt = 0; qt < 2; ++qt)
#pragma unroll
      for (int i = 0; i < 4; ++i)
        qF[qt][i] = *(const bf16x8*)(const void*)(
            Q + (qrow0 + qw + qt * 16 + fr) * 2048 + h * 128 + i * 32 + fh * 8);

    f32x4 acco[8][2] = {};
    float mrun[2] = {-1e30f, -1e30f};
    float lrun[2] = {0.0f, 0.0f};

    stage(0, 0);
#pragma unroll 1
    for (int tt = 0; tt < nt; ++tt) {
      const int c0 = tt * 64;
      if (tt + 1 < nt) {
        stage(tt + 1, (tt + 1) & 1);
        asm volatile("s_waitcnt vmcnt(8)" ::: "memory");
      } else {
        asm volatile("s_waitcnt vmcnt(0)" ::: "memory");
      }
      __builtin_amdgcn_sched_barrier(0);
      __builtin_amdgcn_s_barrier();
      const char* KL = smem + (tt & 1) * 16384;
      const char* VL = smem + 32768 + (tt & 1) * 16384;
      char* PL = smem + 65536 + w * 4096;
      if (c0 <= qw + 31) {  // wave-uniform: wave has unmasked work in this tile
        // ---- S^T = K @ Q^T   (C: col=q=fr, row=kv=fh*4+j within 16-tile)
        f32x4 sacc[2][4] = {};
#pragma unroll
        for (int i = 0; i < 4; ++i)
#pragma unroll
          for (int mt = 0; mt < 4; ++mt) {
            bf16x8 kf = *(const bf16x8*)(const void*)(
                KL + (mt * 16 + fr) * 256 + (((i * 4 + fh) ^ (fr & 7)) * 16));
            sacc[0][mt] = __builtin_amdgcn_mfma_f32_16x16x32_bf16(kf, qF[0][i], sacc[0][mt], 0, 0, 0);
            sacc[1][mt] = __builtin_amdgcn_mfma_f32_16x16x32_bf16(kf, qF[1][i], sacc[1][mt], 0, 0, 0);
          }
        // ---- causal mask (diagonal tiles only)
        if (c0 + 63 > qw) {
#pragma unroll
          for (int qt = 0; qt < 2; ++qt) {
            int qg = qw + qt * 16 + fr;
#pragma unroll
            for (int mt = 0; mt < 4; ++mt)
#pragma unroll
              for (int j = 0; j < 4; ++j)
                if (c0 + mt * 16 + fh * 4 + j > qg) sacc[qt][mt][j] = -1e30f;
          }
        }
        // ---- online softmax per q-column + P pack to LDS
#pragma unroll
        for (int qt = 0; qt < 2; ++qt) {
          float mt_ = -1e30f;
#pragma unroll
          for (int mt = 0; mt < 4; ++mt)
#pragma unroll
            for (int j = 0; j < 4; ++j) mt_ = fmaxf(mt_, sacc[qt][mt][j]);
          mt_ = fmaxf(mt_, __shfl_xor(mt_, 16, 64));
          mt_ = fmaxf(mt_, __shfl_xor(mt_, 32, 64));
          float mnew = fmaxf(mrun[qt], mt_);
          float corr = __expf(mrun[qt] - mnew);
          mrun[qt] = mnew;
          float ps = 0.0f;
          float pv[4][4];
#pragma unroll
          for (int mt = 0; mt < 4; ++mt)
#pragma unroll
            for (int j = 0; j < 4; ++j) {
              float pe = __expf(sacc[qt][mt][j] - mnew);
              pv[mt][j] = pe;
              ps += pe;
            }
          ps += __shfl_xor(ps, 16, 64);
          ps += __shfl_xor(ps, 32, 64);
          lrun[qt] = lrun[qt] * corr + ps;
#pragma unroll
          for (int mt = 0; mt < 4; ++mt) {
            unsigned int u0, u1;
            asm("v_cvt_pk_bf16_f32 %0, %1, %2" : "=v"(u0) : "v"(pv[mt][0]), "v"(pv[mt][1]));
            asm("v_cvt_pk_bf16_f32 %0, %1, %2" : "=v"(u1) : "v"(pv[mt][2]), "v"(pv[mt][3]));
            u32x2 val;
            val[0] = u0;
            val[1] = u1;
            *(u32x2*)(void*)(PL + qt * 2048 + fr * 128 +
                             (((2 * mt + (fh >> 1)) ^ (fr & 7)) * 16) + (fh & 1) * 8) = val;
          }
#pragma unroll
          for (int dt = 0; dt < 8; ++dt) acco[dt][qt] *= corr;
        }
        // ---- O^T += V^T @ P^T
        bf16x8 pf[2][2];
#pragma unroll
        for (int qt = 0; qt < 2; ++qt)
#pragma unroll
          for (int ks = 0; ks < 2; ++ks)
            pf[qt][ks] = *(const bf16x8*)(const void*)(
                PL + qt * 2048 + fr * 128 + (((ks * 4 + fh) ^ (fr & 7)) * 16));
#pragma unroll
        for (int dt = 0; dt < 8; ++dt)
#pragma unroll
          for (int ks = 0; ks < 2; ++ks) {
            bf16x8 vf = *(const bf16x8*)(const void*)(
                VL + (dt * 16 + fr) * 128 + (((ks * 4 + fh) ^ (fr & 7)) * 16));
            acco[dt][0] = __builtin_amdgcn_mfma_f32_16x16x32_bf16(vf, pf[0][ks], acco[dt][0], 0, 0, 0);
            acco[dt][1] = __builtin_amdgcn_mfma_f32_16x16x32_bf16(vf, pf[1][ks], acco[dt][1], 0, 0, 0);
          }
      }
      __builtin_amdgcn_s_barrier();
    }
    // ---- epilogue: O[q][d] = O^T / l
#pragma unroll
    for (int qt = 0; qt < 2; ++qt) {
      float inv = 1.0f / lrun[qt];
      const size_t rb = (qrow0 + qw + qt * 16 + fr) * 2048 + h * 128;
#pragma unroll
      for (int dt = 0; dt < 8; ++dt) {
        ushort4_t o4;
#pragma unroll
        for (int j = 0; j < 4; ++j) o4[j] = f2bf(acco[dt][qt][j] * inv);
        *(ushort4_t*)(void*)(O + rb + dt * 16 + fh * 4) = o4;
      }
    }
  }
}

// ------------------------------------------------- 128^2 GEMM (N=1024 projs)
template <int MODE, typename CT>
__global__ __launch_bounds__(256) void gemm_nt(
    const ushort_t* __restrict__ A, const ushort_t* __restrict__ B,
    CT* __restrict__ C, int M, int N, int K, int lda, int ldb, int ldc,
    long long strA, long long strB, long long strC, int g, float alpha) {
  __shared__ __align__(16) ushort_t sA[128 * 32];
  __shared__ __align__(16) ushort_t sB[128 * 32];
  const int r0 = blockIdx.y * 128;
  const int c0 = blockIdx.x * 128;
  const int bz = blockIdx.z;
  size_t offA = (size_t)(strA * bz);
  size_t offB = (size_t)(strB * bz);
  size_t offC = (size_t)(strC * bz);
  int Keff = K;
  const ushort_t* gA = A + offA;
  const ushort_t* gB = B + offB;
  const int t = threadIdx.x, w = t >> 6, lane = t & 63;
  const int sr = t >> 2;
  const int sc = (t & 3) * 8;
  const int wr = (w >> 1) * 64, wc = (w & 1) * 64;
  const int fr = lane & 15, fk = (lane >> 4) * 8;
  f32x4 acc[4][4] = {};

  for (int k0 = 0; k0 < Keff; k0 += 32) {
#pragma unroll
    for (int i = 0; i < 2; ++i) {
      const int row = i * 64 + sr;
      __builtin_amdgcn_global_load_lds(
          (const AS1 void*)(gA + (size_t)(r0 + row) * lda + k0 + sc),
          (AS3 void*)((char*)sA + i * 4096 + w * 1024), 16, 0, 0);
      __builtin_amdgcn_global_load_lds(
          (const AS1 void*)(gB + (size_t)(c0 + row) * ldb + k0 + sc),
          (AS3 void*)((char*)sB + i * 4096 + w * 1024), 16, 0, 0);
    }
    __syncthreads();
    bf16x8 aF[4], bF[4];
#pragma unroll
    for (int m = 0; m < 4; ++m)
      aF[m] = *(const bf16x8*)(const void*)&sA[(wr + m * 16 + fr) * 32 + fk];
#pragma unroll
    for (int n = 0; n < 4; ++n)
      bF[n] = *(const bf16x8*)(const void*)&sB[(wc + n * 16 + fr) * 32 + fk];
#pragma unroll
    for (int m = 0; m < 4; ++m)
#pragma unroll
      for (int n = 0; n < 4; ++n)
        acc[m][n] = __builtin_amdgcn_mfma_f32_16x16x32_bf16(aF[m], bF[n],
                                                            acc[m][n], 0, 0, 0);
    __syncthreads();
  }

  CT* gC = C + offC;
  const int cr = r0 + wr + (lane >> 4) * 4;
  const int cc = c0 + wc + fr;
#pragma unroll
  for (int m = 0; m < 4; ++m)
#pragma unroll
    for (int n = 0; n < 4; ++n)
#pragma unroll
      for (int j = 0; j < 4; ++j)
        storeC(&gC[(size_t)(cr + m * 16 + j) * ldc + cc + n * 16],
               acc[m][n][j] * alpha);
}

// ------------------------------------------- 256^2 8-phase GEMM (T1..T5)
template <typename CT>
__global__ __launch_bounds__(512, 2) void gemm256(
    const ushort_t* __restrict__ A, const ushort_t* __restrict__ B,
    CT* __restrict__ C, int K, int lda, int ldb, int ldc,
    int nwgx, int nwg, long long strA, long long strB, long long strC) {
  __shared__ __align__(16) char smem[131072];
  const int bz = blockIdx.y;
  const int bid = blockIdx.x;
  const int swz = (bid & 7) * (nwg >> 3) + (bid >> 3);
  const int r0 = (swz / nwgx) * 256;
  const int c0 = (swz % nwgx) * 256;
  const int t = threadIdx.x, w = t >> 6, lane = t & 63;
  const int wm = w >> 2, wn = w & 3;
  const int fr = lane & 15, fh = lane >> 4;
  const int sl0 = (fh ^ (fr & 7)) << 4;
  const int ldsw = w * 1024;
  const int srow = t >> 3;
  const int scb = (t & 7) ^ (srow & 7);
  const int NT = K >> 6;
  const ushort_t* gA = A + strA * bz + (size_t)(r0 + srow) * lda + scb * 8;
  const ushort_t* gB = B + strB * bz + (size_t)(c0 + srow) * ldb + scb * 8;

  auto stage = [&](int tile, int isB, int h) {
    const ushort_t* g = isB ? gB : gA;
    const size_t ld = isB ? (size_t)ldb : (size_t)lda;
    char* lp = (char*)smem + ((tile & 1) << 16) + (isB ? 32768 : 0) + (h << 14) + ldsw;
    const ushort_t* src = g + (size_t)(h * 128) * ld + tile * 64;
    __builtin_amdgcn_global_load_lds((const AS1 void*)src, (AS3 void*)lp, 16, 0, 0);
    __builtin_amdgcn_global_load_lds((const AS1 void*)(src + 64 * ld),
                                     (AS3 void*)(lp + 8192), 16, 0, 0);
  };

  f32x4 acc[8][4] = {};

  stage(0, 0, 0); stage(0, 0, 1); stage(0, 1, 0); stage(0, 1, 1);
  if (NT > 1) {
    stage(1, 0, 0); stage(1, 0, 1);
    asm volatile("s_waitcnt vmcnt(4)" ::: "memory");
  } else {
    asm volatile("s_waitcnt vmcnt(0)" ::: "memory");
  }
  __builtin_amdgcn_sched_barrier(0);
  __builtin_amdgcn_s_barrier();

  const int aOff = wm * 16384 + fr * 128;
  const int bOff = 32768 + wn * 8192 + fr * 128;

  for (int kt = 0; kt < NT; ++kt) {
    const int buf = (kt & 1) << 16;
    const char* la = (const char*)smem + buf + aOff;
    const char* lb = (const char*)smem + buf + bOff;
    bf16x8 aF0[8], aF1[8], bF0[4], bF1[4];
#pragma unroll
    for (int m = 0; m < 8; ++m)
      aF0[m] = *(const bf16x8*)(const void*)(la + m * 2048 + sl0);
#pragma unroll
    for (int n = 0; n < 4; ++n)
      bF0[n] = *(const bf16x8*)(const void*)(lb + n * 2048 + sl0);
    if (kt + 1 < NT) stage(kt + 1, 1, 0);
    __builtin_amdgcn_s_barrier();
    asm volatile("s_waitcnt lgkmcnt(0)" ::: "memory");
    __builtin_amdgcn_sched_barrier(0);
    __builtin_amdgcn_s_setprio(1);
#pragma unroll
    for (int m = 0; m < 4; ++m)
#pragma unroll
      for (int n = 0; n < 4; ++n)
        acc[m][n] = __builtin_amdgcn_mfma_f32_16x16x32_bf16(aF0[m], bF0[n], acc[m][n], 0, 0, 0);
    __builtin_amdgcn_s_setprio(0);
    __builtin_amdgcn_s_barrier();
#pragma unroll
    for (int m = 0; m < 8; ++m)
      aF1[m] = *(const bf16x8*)(const void*)(la + m * 2048 + (sl0 ^ 64));
#pragma unroll
    for (int n = 0; n < 4; ++n)
      bF1[n] = *(const bf16x8*)(const void*)(lb + n * 2048 + (sl0 ^ 64));
    if (kt + 1 < NT) stage(kt + 1, 1, 1);
    __builtin_amdgcn_s_barrier();
    asm volatile("s_waitcnt lgkmcnt(0)" ::: "memory");
    __builtin_amdgcn_sched_barrier(0);
    __builtin_amdgcn_s_setprio(1);
#pragma unroll
    for (int m = 4; m < 8; ++m)
#pragma unroll
      for (int n = 0; n < 4; ++n)
        acc[m][n] = __builtin_amdgcn_mfma_f32_16x16x32_bf16(aF0[m], bF0[n], acc[m][n], 0, 0, 0);
    __builtin_amdgcn_s_setprio(0);
    __builtin_amdgcn_s_barrier();
    if (kt + 2 < NT) stage(kt + 2, 0, 0);
    __builtin_amdgcn_s_barrier();
    __builtin_amdgcn_s_setprio(1);
#pragma unroll
    for (int m = 0; m < 4; ++m)
#pragma unroll
      for (int n = 0; n < 4; ++n)
        acc[m][n] = __builtin_amdgcn_mfma_f32_16x16x32_bf16(aF1[m], bF1[n], acc[m][n], 0, 0, 0);
    __builtin_amdgcn_s_setprio(0);
    __builtin_amdgcn_s_barrier();
    if (kt + 2 < NT) stage(kt + 2, 0, 1);
    __builtin_amdgcn_s_setprio(1);
#pragma unroll
    for (int m = 4; m < 8; ++m)
#pragma unroll
      for (int n = 0; n < 4; ++n)
        acc[m][n] = __builtin_amdgcn_mfma_f32_16x16x32_bf16(aF1[m], bF1[n], acc[m][n], 0, 0, 0);
    __builtin_amdgcn_s_setprio(0);
    if (kt + 2 < NT)
      asm volatile("s_waitcnt vmcnt(4)" ::: "memory");
    else if (kt + 1 < NT)
      asm volatile("s_waitcnt vmcnt(0)" ::: "memory");
    __builtin_amdgcn_sched_barrier(0);
    __builtin_amdgcn_s_barrier();
  }

  CT* gC = C + strC * bz;
  const int cr = r0 + wm * 128 + fh * 4;
  const int cc = c0 + wn * 64 + fr;
#pragma unroll
  for (int m = 0; m < 8; ++m)
#pragma unroll
    for (int n = 0; n < 4; ++n)
#pragma unroll
      for (int j = 0; j < 4; ++j)
        storeC(&gC[(size_t)(cr + m * 16 + j) * ldc + cc + n * 16], acc[m][n][j]);
}

// ---------------------------------------------------------------- host
extern "C" void kernel_launch(void* const* d_in, const int* in_sizes, int n_in,
                              void* d_out, int out_size, void* d_ws, size_t ws_size,
                              hipStream_t stream) {
  const float* x = (const float*)d_in[0];
  const float* wq = (const float*)d_in[1];
  const float* wk1 = (const float*)d_in[2];
  const float* wk2 = (const float*)d_in[3];
  const float* wk3 = (const float*)d_in[4];
  const float* wv1 = (const float*)d_in[5];
  const float* wv2 = (const float*)d_in[6];
  const float* wv3 = (const float*)d_in[7];
  const float* wo = (const float*)d_in[8];
  const float* fc = (const float*)d_in[9];
  const float* fs = (const float*)d_in[10];

  float* outp = (float*)d_out;
  float* okeys = outp + 8388608;
  float* ovals = outp + 12582912;

  char* p = (char*)d_ws;
  auto alloc = [&](size_t bytes) {
    char* r = p;
    p += (bytes + 255) & ~(size_t)255;
    return r;
  };
  ushort_t* xb = (ushort_t*)alloc(4096ull * 2048 * 2);
  ushort_t* wqT = (ushort_t*)alloc(2048ull * 2048 * 2);
  ushort_t* wk1T = (ushort_t*)alloc(8192ull * 2048 * 2);  // wk3T adjacent
  ushort_t* wk3T = (ushort_t*)alloc(8192ull * 2048 * 2);
  ushort_t* wk2T = (ushort_t*)alloc(1024ull * 8192 * 2);
  ushort_t* wv1T = (ushort_t*)alloc(8192ull * 2048 * 2);  // wv3T adjacent
  ushort_t* wv3T = (ushort_t*)alloc(8192ull * 2048 * 2);
  ushort_t* wv2T = (ushort_t*)alloc(1024ull * 8192 * 2);
  ushort_t* woT = (ushort_t*)alloc(2048ull * 2048 * 2);
  ushort_t* qb = (ushort_t*)alloc(4096ull * 2048 * 2);
  ushort_t* kb = (ushort_t*)alloc(4096ull * 1024 * 2);
  ushort_t* vb = (ushort_t*)alloc(4096ull * 1024 * 2);
  ushort_t* vbT = (ushort_t*)alloc(4096ull * 1024 * 2);
  ushort_t* ob = (ushort_t*)alloc(4096ull * 2048 * 2);
  char* hreg = alloc(134217728ull);
  ushort_t* h1 = (ushort_t*)hreg;
  ushort_t* h3 = (ushort_t*)(hreg + 67108864);

  dim3 tb(32, 8);

  cast_f32_bf16<<<8192, 256, 0, stream>>>(x, xb);
  transpose_cast<<<dim3(64, 64), tb, 0, stream>>>(wq, wqT, 2048, 2048);
  transpose_cast<<<dim3(256, 64), tb, 0, stream>>>(wk1, wk1T, 2048, 8192);
  transpose_cast<<<dim3(32, 256), tb, 0, stream>>>(wk2, wk2T, 8192, 1024);
  transpose_cast<<<dim3(256, 64), tb, 0, stream>>>(wk3, wk3T, 2048, 8192);
  transpose_cast<<<dim3(256, 64), tb, 0, stream>>>(wv1, wv1T, 2048, 8192);
  transpose_cast<<<dim3(32, 256), tb, 0, stream>>>(wv2, wv2T, 8192, 1024);
  transpose_cast<<<dim3(256, 64), tb, 0, stream>>>(wv3, wv3T, 2048, 8192);
  transpose_cast<<<dim3(64, 64), tb, 0, stream>>>(wo, woT, 2048, 2048);

  // q projection + rope (scale folded)
  gemm256<ushort_t><<<dim3(128, 1), 512, 0, stream>>>(
      xb, wqT, qb, 2048, 2048, 2048, 2048, 8, 128, 0, 0, 0);
  rope_q<<<16384, 256, 0, stream>>>(qb, fc, fs);

  // k gates (batched z=2: h1 = x@wk1, h3 = x@wk3)
  gemm256<ushort_t><<<dim3(512, 2), 512, 0, stream>>>(
      xb, wk1T, h1, 2048, 2048, 2048, 8192, 32, 512, 0, 16777216, 33554432);
  silu_mul<<<16384, 256, 0, stream>>>(h1, h3);
  gemm_nt<0, ushort_t><<<dim3(8, 32, 1), 256, 0, stream>>>(
      h1, wk2T, kb, 4096, 1024, 8192, 8192, 8192, 1024, 0, 0, 0, 0, 1.0f);
  rope_k<<<8192, 256, 0, stream>>>(kb, okeys, fc, fs);

  // v gates
  gemm256<ushort_t><<<dim3(512, 2), 512, 0, stream>>>(
      xb, wv1T, h1, 2048, 2048, 2048, 8192, 32, 512, 0, 16777216, 33554432);
  silu_mul<<<16384, 256, 0, stream>>>(h1, h3);
  gemm_nt<0, ushort_t><<<dim3(8, 32, 1), 256, 0, stream>>>(
      h1, wv2T, vb, 4096, 1024, 8192, 8192, 8192, 1024, 0, 0, 0, 0, 1.0f);
  v_post<<<dim3(64, 4, 16), tb, 0, stream>>>(vb, ovals, vbT);

  // fused flash attention (replaces QK^T / softmax / PV pipeline)
  flash_attn<<<dim3(8, 32), 256, 0, stream>>>(qb, kb, vbT, ob);

  // output projection
  gemm256<float><<<dim3(128, 1), 512, 0, stream>>>(
      ob, woT, outp, 2048, 2048, 2048, 2048, 8, 128, 0, 0, 0);

  (void)in_sizes; (void)n_in; (void)out_size; (void)ws_size;
}

// Round 4
// 1048.043 us; speedup vs baseline: 2.1071x; 1.3027x over previous
//
#include <hip/hip_runtime.h>

typedef unsigned short ushort_t;
typedef __attribute__((ext_vector_type(4))) float f32x4;
typedef __attribute__((ext_vector_type(8))) __bf16 bf16x8;
typedef __attribute__((ext_vector_type(4))) unsigned short ushort4_t;
typedef __attribute__((ext_vector_type(8))) unsigned short ushort8_t;
typedef __attribute__((ext_vector_type(2))) unsigned int u32x2;

#define AS1 __attribute__((address_space(1)))
#define AS3 __attribute__((address_space(3)))

__device__ __forceinline__ float bf2f(ushort_t u) {
  unsigned int v = ((unsigned int)u) << 16;
  return __builtin_bit_cast(float, v);
}
__device__ __forceinline__ ushort_t f2bf(float f) {
  unsigned int u = __builtin_bit_cast(unsigned int, f);
  u += 0x7fffu + ((u >> 16) & 1u);
  return (ushort_t)(u >> 16);
}
__device__ __forceinline__ void storeC(float* p, float v) { *p = v; }
__device__ __forceinline__ void storeC(ushort_t* p, float v) { *p = f2bf(v); }

// ---------------------------------------------------------------- elementwise
__global__ __launch_bounds__(256) void cast_f32_bf16(const float* __restrict__ in,
                                                     ushort_t* __restrict__ outp) {
  size_t i = ((size_t)blockIdx.x * 256 + threadIdx.x) * 4;
  f32x4 v = *(const f32x4*)(const void*)&in[i];
  ushort4_t o;
#pragma unroll
  for (int j = 0; j < 4; ++j) o[j] = f2bf(v[j]);
  *(ushort4_t*)(void*)&outp[i] = o;
}

// batched W[K][N] f32 -> Wt[N][K] bf16 (z selects source, strT strides output)
__global__ __launch_bounds__(256) void transpose_cast_b(
    const float* __restrict__ W0, const float* __restrict__ W1,
    const float* __restrict__ W2, const float* __restrict__ W3,
    ushort_t* __restrict__ Wt, int K, int N, long long strT) {
  __shared__ float tile[32][33];
  const int z = blockIdx.z;
  const float* W = (z == 0) ? W0 : (z == 1) ? W1 : (z == 2) ? W2 : W3;
  ushort_t* out = Wt + (size_t)(strT * z);
  int n0 = blockIdx.x * 32, k0 = blockIdx.y * 32;
  int tx = threadIdx.x, ty = threadIdx.y;
#pragma unroll
  for (int i = 0; i < 4; ++i)
    tile[ty + 8 * i][tx] = W[(size_t)(k0 + ty + 8 * i) * N + n0 + tx];
  __syncthreads();
#pragma unroll
  for (int i = 0; i < 4; ++i)
    out[(size_t)(n0 + ty + 8 * i) * K + k0 + tx] = f2bf(tile[tx][ty + 8 * i]);
}

__global__ __launch_bounds__(256) void silu_mul(ushort_t* __restrict__ h1,
                                                const ushort_t* __restrict__ h3) {
  size_t i = ((size_t)blockIdx.x * 256 + threadIdx.x) * 8;
  ushort8_t a = *(const ushort8_t*)(const void*)&h1[i];
  ushort8_t b = *(const ushort8_t*)(const void*)&h3[i];
#pragma unroll
  for (int j = 0; j < 8; ++j) {
    float x = bf2f(a[j]);
    float g = x / (1.0f + __expf(-x));
    a[j] = f2bf(g * bf2f(b[j]));
  }
  *(ushort8_t*)(void*)&h1[i] = a;
}

// ------------------------------------------------- split-K reduce kernels
// partQ: [2][4096][2048] f32 -> qb bf16 with rope + qk_scale folded
__global__ __launch_bounds__(256) void reduce_q(const float* __restrict__ part,
                                                ushort_t* __restrict__ qb,
                                                const float* __restrict__ fc,
                                                const float* __restrict__ fs) {
  const float alpha = 0.08838834764831845f;  // 1/sqrt(128)
  int p = blockIdx.x * 256 + threadIdx.x;    // 0..4194303
  int i = p & 63;
  int h = (p >> 6) & 15;
  int row = p >> 10;
  int s = row & 2047;
  size_t src = (size_t)row * 2048 + h * 128 + 2 * i;
  float xr = part[src] + part[src + 8388608];
  float xi = part[src + 1] + part[src + 8388609];
  float c = fc[s * 64 + i] * alpha, sn = fs[s * 64 + i] * alpha;
  qb[src] = f2bf(xr * c - xi * sn);
  qb[src + 1] = f2bf(xr * sn + xi * c);
}

// partK: [4][4096][1024] f32 -> kb bf16 + okeys f32, rope applied
__global__ __launch_bounds__(256) void reduce_k(const float* __restrict__ part,
                                                ushort_t* __restrict__ kb,
                                                float* __restrict__ okeys,
                                                const float* __restrict__ fc,
                                                const float* __restrict__ fs) {
  int p = blockIdx.x * 256 + threadIdx.x;  // 0..2097151
  int i = p & 63;
  int kh = (p >> 6) & 7;
  int row = p >> 9;
  int s = row & 2047;
  size_t src = (size_t)row * 1024 + kh * 128 + 2 * i;
  float xr = part[src] + part[src + 4194304] + part[src + 8388608] + part[src + 12582912];
  float xi = part[src + 1] + part[src + 1 + 4194304] + part[src + 1 + 8388608] +
             part[src + 1 + 12582912];
  float c = fc[s * 64 + i], sn = fs[s * 64 + i];
  float orr = xr * c - xi * sn;
  float oi = xr * sn + xi * c;
  kb[src] = f2bf(orr);
  kb[src + 1] = f2bf(oi);
  okeys[src] = orr;
  okeys[src + 1] = oi;
}

// partV: [4][4096][1024] f32 -> ovals f32 + vbT[(b*8+kh)*128+d][s] bf16
__global__ __launch_bounds__(256) void reduce_v(const float* __restrict__ part,
                                                float* __restrict__ ovals,
                                                ushort_t* __restrict__ vbT) {
  __shared__ ushort_t tile[32][33];
  int s0 = blockIdx.x * 32, d0 = blockIdx.y * 32, bk = blockIdx.z;
  int b = bk >> 3, kh = bk & 7;
  int tx = threadIdx.x, ty = threadIdx.y;
#pragma unroll
  for (int i = 0; i < 4; ++i) {
    int s = s0 + ty + 8 * i;
    size_t src = ((size_t)(b * 2048 + s)) * 1024 + kh * 128 + d0 + tx;
    float v = part[src] + part[src + 4194304] + part[src + 8388608] + part[src + 12582912];
    tile[ty + 8 * i][tx] = f2bf(v);
    ovals[src] = v;
  }
  __syncthreads();
#pragma unroll
  for (int i = 0; i < 4; ++i) {
    int d = d0 + ty + 8 * i;
    vbT[((size_t)bk * 128 + d) * 2048 + s0 + tx] = tile[tx][ty + 8 * i];
  }
}

// partO: [2][4096][2048] f32 -> outp f32
__global__ __launch_bounds__(256) void reduce_wo(const float* __restrict__ part,
                                                 float* __restrict__ outp) {
  size_t i = ((size_t)blockIdx.x * 256 + threadIdx.x) * 4;
  f32x4 a = *(const f32x4*)(const void*)&part[i];
  f32x4 b = *(const f32x4*)(const void*)&part[i + 8388608];
  *(f32x4*)(void*)&outp[i] = a + b;
}

// ---------------------------------------------------------------- flash attn
__global__ __launch_bounds__(256) void flash_attn(
    const ushort_t* __restrict__ Q, const ushort_t* __restrict__ Kg,
    const ushort_t* __restrict__ VT, ushort_t* __restrict__ O) {
  __shared__ __align__(16) char smem[81920];  // K dbuf 32K | V dbuf 32K | P 16K
  const int xp = blockIdx.x;
  const int bh = blockIdx.y;
  const int b = bh >> 4, h = bh & 15, kh = h >> 1;
  const int t = threadIdx.x, w = t >> 6, lane = t & 63;
  const int fr = lane & 15, fh = lane >> 4;
  const size_t kelem0 = ((size_t)b * 2048) * 1024 + kh * 128;
  const size_t velem0 = ((size_t)(b * 8 + kh)) * 128 * 2048;
  const size_t qrow0 = (size_t)b * 2048;

  size_t oK[4], oV[4];
#pragma unroll
  for (int qv = 0; qv < 4; ++qv) {
    int row = w * 16 + qv * 4 + (lane >> 4);
    oK[qv] = (size_t)row * 1024 + (((lane & 15) ^ (row & 7)) * 8);
    int rd = w * 32 + qv * 8 + (lane >> 3);
    oV[qv] = (size_t)rd * 2048 + (((lane & 7) ^ (rd & 7)) * 8);
  }

  auto stage = [&](int tile, int buf) {
    const size_t kc = (size_t)tile * 64 * 1024;
    const int vc = tile * 64;
    char* kd = smem + buf * 16384 + w * 4096;
    char* vd = smem + 32768 + buf * 16384 + w * 4096;
#pragma unroll
    for (int qv = 0; qv < 4; ++qv) {
      __builtin_amdgcn_global_load_lds((const AS1 void*)(Kg + kelem0 + kc + oK[qv]),
                                       (AS3 void*)(kd + qv * 1024), 16, 0, 0);
      __builtin_amdgcn_global_load_lds((const AS1 void*)(VT + velem0 + oV[qv] + vc),
                                       (AS3 void*)(vd + qv * 1024), 16, 0, 0);
    }
  };

#pragma unroll 1
  for (int ph = 0; ph < 2; ++ph) {
    const int qi = ph ? (15 - xp) : xp;
    const int qw = qi * 128 + w * 32;
    const int nt = 2 * qi + 2;

    bf16x8 qF[2][4];
#pragma unroll
    for (int qt = 0; qt < 2; ++qt)
#pragma unroll
      for (int i = 0; i < 4; ++i)
        qF[qt][i] = *(const bf16x8*)(const void*)(
            Q + (qrow0 + qw + qt * 16 + fr) * 2048 + h * 128 + i * 32 + fh * 8);

    f32x4 acco[8][2] = {};
    float mrun[2] = {-1e30f, -1e30f};
    float lrun[2] = {0.0f, 0.0f};

    stage(0, 0);
#pragma unroll 1
    for (int tt = 0; tt < nt; ++tt) {
      const int c0 = tt * 64;
      if (tt + 1 < nt) {
        stage(tt + 1, (tt + 1) & 1);
        asm volatile("s_waitcnt vmcnt(8)" ::: "memory");
      } else {
        asm volatile("s_waitcnt vmcnt(0)" ::: "memory");
      }
      __builtin_amdgcn_sched_barrier(0);
      __builtin_amdgcn_s_barrier();
      const char* KL = smem + (tt & 1) * 16384;
      const char* VL = smem + 32768 + (tt & 1) * 16384;
      char* PL = smem + 65536 + w * 4096;
      if (c0 <= qw + 31) {
        f32x4 sacc[2][4] = {};
#pragma unroll
        for (int i = 0; i < 4; ++i)
#pragma unroll
          for (int mt = 0; mt < 4; ++mt) {
            bf16x8 kf = *(const bf16x8*)(const void*)(
                KL + (mt * 16 + fr) * 256 + (((i * 4 + fh) ^ (fr & 7)) * 16));
            sacc[0][mt] = __builtin_amdgcn_mfma_f32_16x16x32_bf16(kf, qF[0][i], sacc[0][mt], 0, 0, 0);
            sacc[1][mt] = __builtin_amdgcn_mfma_f32_16x16x32_bf16(kf, qF[1][i], sacc[1][mt], 0, 0, 0);
          }
        if (c0 + 63 > qw) {
#pragma unroll
          for (int qt = 0; qt < 2; ++qt) {
            int qg = qw + qt * 16 + fr;
#pragma unroll
            for (int mt = 0; mt < 4; ++mt)
#pragma unroll
              for (int j = 0; j < 4; ++j)
                if (c0 + mt * 16 + fh * 4 + j > qg) sacc[qt][mt][j] = -1e30f;
          }
        }
#pragma unroll
        for (int qt = 0; qt < 2; ++qt) {
          float mt_ = -1e30f;
#pragma unroll
          for (int mt = 0; mt < 4; ++mt)
#pragma unroll
            for (int j = 0; j < 4; ++j) mt_ = fmaxf(mt_, sacc[qt][mt][j]);
          mt_ = fmaxf(mt_, __shfl_xor(mt_, 16, 64));
          mt_ = fmaxf(mt_, __shfl_xor(mt_, 32, 64));
          float mnew = fmaxf(mrun[qt], mt_);
          float corr = __expf(mrun[qt] - mnew);
          mrun[qt] = mnew;
          float ps = 0.0f;
          float pv[4][4];
#pragma unroll
          for (int mt = 0; mt < 4; ++mt)
#pragma unroll
            for (int j = 0; j < 4; ++j) {
              float pe = __expf(sacc[qt][mt][j] - mnew);
              pv[mt][j] = pe;
              ps += pe;
            }
          ps += __shfl_xor(ps, 16, 64);
          ps += __shfl_xor(ps, 32, 64);
          lrun[qt] = lrun[qt] * corr + ps;
#pragma unroll
          for (int mt = 0; mt < 4; ++mt) {
            unsigned int u0, u1;
            asm("v_cvt_pk_bf16_f32 %0, %1, %2" : "=v"(u0) : "v"(pv[mt][0]), "v"(pv[mt][1]));
            asm("v_cvt_pk_bf16_f32 %0, %1, %2" : "=v"(u1) : "v"(pv[mt][2]), "v"(pv[mt][3]));
            u32x2 val;
            val[0] = u0;
            val[1] = u1;
            *(u32x2*)(void*)(PL + qt * 2048 + fr * 128 +
                             (((2 * mt + (fh >> 1)) ^ (fr & 7)) * 16) + (fh & 1) * 8) = val;
          }
#pragma unroll
          for (int dt = 0; dt < 8; ++dt) acco[dt][qt] *= corr;
        }
        bf16x8 pf[2][2];
#pragma unroll
        for (int qt = 0; qt < 2; ++qt)
#pragma unroll
          for (int ks = 0; ks < 2; ++ks)
            pf[qt][ks] = *(const bf16x8*)(const void*)(
                PL + qt * 2048 + fr * 128 + (((ks * 4 + fh) ^ (fr & 7)) * 16));
#pragma unroll
        for (int dt = 0; dt < 8; ++dt)
#pragma unroll
          for (int ks = 0; ks < 2; ++ks) {
            bf16x8 vf = *(const bf16x8*)(const void*)(
                VL + (dt * 16 + fr) * 128 + (((ks * 4 + fh) ^ (fr & 7)) * 16));
            acco[dt][0] = __builtin_amdgcn_mfma_f32_16x16x32_bf16(vf, pf[0][ks], acco[dt][0], 0, 0, 0);
            acco[dt][1] = __builtin_amdgcn_mfma_f32_16x16x32_bf16(vf, pf[1][ks], acco[dt][1], 0, 0, 0);
          }
      }
      __builtin_amdgcn_s_barrier();
    }
#pragma unroll
    for (int qt = 0; qt < 2; ++qt) {
      float inv = 1.0f / lrun[qt];
      const size_t rb = (qrow0 + qw + qt * 16 + fr) * 2048 + h * 128;
#pragma unroll
      for (int dt = 0; dt < 8; ++dt) {
        ushort4_t o4;
#pragma unroll
        for (int j = 0; j < 4; ++j) o4[j] = f2bf(acco[dt][qt][j] * inv);
        *(ushort4_t*)(void*)(O + rb + dt * 16 + fh * 4) = o4;
      }
    }
  }
}

// ------------------------------------------- 256^2 8-phase GEMM, deep prefetch
// C[M][N] = A[M][K] @ B[N][K]^T. Both A and B staged 2 K-tiles ahead (phases
// 3/4 write tile kt+2 into the buffer being read — safe: all reads of it are
// lgkmcnt-fenced by phase 2's barrier pair). Counted vmcnt(8) once per iter.
template <typename CT>
__global__ __launch_bounds__(512, 2) void gemm256(
    const ushort_t* __restrict__ A, const ushort_t* __restrict__ B,
    CT* __restrict__ C, int K, int lda, int ldb, int ldc,
    int nwgx, int nwg, long long strA, long long strB, long long strC) {
  __shared__ __align__(16) char smem[131072];
  const int bz = blockIdx.y;
  const int bid = blockIdx.x;
  const int swz = (bid & 7) * (nwg >> 3) + (bid >> 3);  // bijective: nwg%8==0
  const int r0 = (swz / nwgx) * 256;
  const int c0 = (swz % nwgx) * 256;
  const int t = threadIdx.x, w = t >> 6, lane = t & 63;
  const int wm = w >> 2, wn = w & 3;
  const int fr = lane & 15, fh = lane >> 4;
  const int sl0 = (fh ^ (fr & 7)) << 4;
  const int ldsw = w * 1024;
  const int srow = t >> 3;
  const int scb = (t & 7) ^ (srow & 7);
  const int NT = K >> 6;
  const ushort_t* gA = A + strA * bz + (size_t)(r0 + srow) * lda + scb * 8;
  const ushort_t* gB = B + strB * bz + (size_t)(c0 + srow) * ldb + scb * 8;

  auto stage = [&](int tile, int isB, int h) {
    const ushort_t* g = isB ? gB : gA;
    const size_t ld = isB ? (size_t)ldb : (size_t)lda;
    char* lp = (char*)smem + ((tile & 1) << 16) + (isB ? 32768 : 0) + (h << 14) + ldsw;
    const ushort_t* src = g + (size_t)(h * 128) * ld + tile * 64;
    __builtin_amdgcn_global_load_lds((const AS1 void*)src, (AS3 void*)lp, 16, 0, 0);
    __builtin_amdgcn_global_load_lds((const AS1 void*)(src + 64 * ld),
                                     (AS3 void*)(lp + 8192), 16, 0, 0);
  };

  f32x4 acc[8][4] = {};

  // prologue: tile0 -> buf0 (8 loads), tile1 -> buf1 (8 loads)
  stage(0, 0, 0); stage(0, 0, 1); stage(0, 1, 0); stage(0, 1, 1);
  if (NT > 1) {
    stage(1, 0, 0); stage(1, 0, 1); stage(1, 1, 0); stage(1, 1, 1);
    asm volatile("s_waitcnt vmcnt(8)" ::: "memory");  // tile0 landed
  } else {
    asm volatile("s_waitcnt vmcnt(0)" ::: "memory");
  }
  __builtin_amdgcn_sched_barrier(0);
  __builtin_amdgcn_s_barrier();

  const int aOff = wm * 16384 + fr * 128;
  const int bOff = 32768 + wn * 8192 + fr * 128;

  for (int kt = 0; kt < NT; ++kt) {
    const int buf = (kt & 1) << 16;
    const char* la = (const char*)smem + buf + aOff;
    const char* lb = (const char*)smem + buf + bOff;
    bf16x8 aF0[8], aF1[8], bF0[4], bF1[4];
    // ---- phase 1: read k0 frags; MFMA k0 m0-3
#pragma unroll
    for (int m = 0; m < 8; ++m)
      aF0[m] = *(const bf16x8*)(const void*)(la + m * 2048 + sl0);
#pragma unroll
    for (int n = 0; n < 4; ++n)
      bF0[n] = *(const bf16x8*)(const void*)(lb + n * 2048 + sl0);
    __builtin_amdgcn_s_barrier();
    asm volatile("s_waitcnt lgkmcnt(0)" ::: "memory");
    __builtin_amdgcn_sched_barrier(0);
    __builtin_amdgcn_s_setprio(1);
#pragma unroll
    for (int m = 0; m < 4; ++m)
#pragma unroll
      for (int n = 0; n < 4; ++n)
        acc[m][n] = __builtin_amdgcn_mfma_f32_16x16x32_bf16(aF0[m], bF0[n], acc[m][n], 0, 0, 0);
    __builtin_amdgcn_s_setprio(0);
    __builtin_amdgcn_s_barrier();
    // ---- phase 2: read k1 frags; MFMA k0 m4-7
#pragma unroll
    for (int m = 0; m < 8; ++m)
      aF1[m] = *(const bf16x8*)(const void*)(la + m * 2048 + (sl0 ^ 64));
#pragma unroll
    for (int n = 0; n < 4; ++n)
      bF1[n] = *(const bf16x8*)(const void*)(lb + n * 2048 + (sl0 ^ 64));
    __builtin_amdgcn_s_barrier();
    asm volatile("s_waitcnt lgkmcnt(0)" ::: "memory");
    __builtin_amdgcn_sched_barrier(0);
    __builtin_amdgcn_s_setprio(1);
#pragma unroll
    for (int m = 4; m < 8; ++m)
#pragma unroll
      for (int n = 0; n < 4; ++n)
        acc[m][n] = __builtin_amdgcn_mfma_f32_16x16x32_bf16(aF0[m], bF0[n], acc[m][n], 0, 0, 0);
    __builtin_amdgcn_s_setprio(0);
    __builtin_amdgcn_s_barrier();
    // ---- phase 3: stage tile kt+2 half 0 (A+B); MFMA k1 m0-3
    if (kt + 2 < NT) { stage(kt + 2, 0, 0); stage(kt + 2, 1, 0); }
    __builtin_amdgcn_s_barrier();
    __builtin_amdgcn_s_setprio(1);
#pragma unroll
    for (int m = 0; m < 4; ++m)
#pragma unroll
      for (int n = 0; n < 4; ++n)
        acc[m][n] = __builtin_amdgcn_mfma_f32_16x16x32_bf16(aF1[m], bF1[n], acc[m][n], 0, 0, 0);
    __builtin_amdgcn_s_setprio(0);
    __builtin_amdgcn_s_barrier();
    // ---- phase 4: stage tile kt+2 half 1 (A+B); MFMA k1 m4-7; counted vmcnt
    if (kt + 2 < NT) { stage(kt + 2, 0, 1); stage(kt + 2, 1, 1); }
    __builtin_amdgcn_s_setprio(1);
#pragma unroll
    for (int m = 4; m < 8; ++m)
#pragma unroll
      for (int n = 0; n < 4; ++n)
        acc[m][n] = __builtin_amdgcn_mfma_f32_16x16x32_bf16(aF1[m], bF1[n], acc[m][n], 0, 0, 0);
    __builtin_amdgcn_s_setprio(0);
    if (kt + 2 < NT)
      asm volatile("s_waitcnt vmcnt(8)" ::: "memory");   // tile kt+1 landed
    else if (kt + 1 < NT)
      asm volatile("s_waitcnt vmcnt(0)" ::: "memory");
    __builtin_amdgcn_sched_barrier(0);
    __builtin_amdgcn_s_barrier();
  }

  CT* gC = C + strC * bz;
  const int cr = r0 + wm * 128 + fh * 4;
  const int cc = c0 + wn * 64 + fr;
#pragma unroll
  for (int m = 0; m < 8; ++m)
#pragma unroll
    for (int n = 0; n < 4; ++n)
#pragma unroll
      for (int j = 0; j < 4; ++j)
        storeC(&gC[(size_t)(cr + m * 16 + j) * ldc + cc + n * 16], acc[m][n][j]);
}

// ---------------------------------------------------------------- host
extern "C" void kernel_launch(void* const* d_in, const int* in_sizes, int n_in,
                              void* d_out, int out_size, void* d_ws, size_t ws_size,
                              hipStream_t stream) {
  const float* x = (const float*)d_in[0];
  const float* wq = (const float*)d_in[1];
  const float* wk1 = (const float*)d_in[2];
  const float* wk2 = (const float*)d_in[3];
  const float* wk3 = (const float*)d_in[4];
  const float* wv1 = (const float*)d_in[5];
  const float* wv2 = (const float*)d_in[6];
  const float* wv3 = (const float*)d_in[7];
  const float* wo = (const float*)d_in[8];
  const float* fc = (const float*)d_in[9];
  const float* fs = (const float*)d_in[10];

  float* outp = (float*)d_out;
  float* okeys = outp + 8388608;
  float* ovals = outp + 12582912;

  char* p = (char*)d_ws;
  auto alloc = [&](size_t bytes) {
    char* r = p;
    p += (bytes + 255) & ~(size_t)255;
    return r;
  };
  ushort_t* xb = (ushort_t*)alloc(8388608ull * 2);
  ushort_t* w4T = (ushort_t*)alloc(4ull * 16777216 * 2);  // wk1T|wk3T|wv1T|wv3T
  ushort_t* w2T = (ushort_t*)alloc(2ull * 8388608 * 2);   // wk2T|wv2T
  ushort_t* wqoT = (ushort_t*)alloc(2ull * 4194304 * 2);  // wqT|woT
  ushort_t* qb = (ushort_t*)alloc(8388608ull * 2);
  ushort_t* kb = (ushort_t*)alloc(4194304ull * 2);
  ushort_t* vbT = (ushort_t*)alloc(4194304ull * 2);
  ushort_t* ob = (ushort_t*)alloc(8388608ull * 2);
  char* hreg = alloc(134217728ull);
  ushort_t* h1 = (ushort_t*)hreg;                     // gate output / silu out
  float* part67 = (float*)(hreg + 67108864);          // h3 region / splitK parts
  float* partQO = (float*)hreg;                       // q/wo splitK parts

  ushort_t* wk1T = w4T;
  ushort_t* wk2T = w2T;
  ushort_t* wv1T = w4T + 2ull * 16777216;
  ushort_t* wv2T = w2T + 8388608;
  ushort_t* wqT = wqoT;
  ushort_t* woT = wqoT + 4194304;

  dim3 tb(32, 8);

  cast_f32_bf16<<<8192, 256, 0, stream>>>(x, xb);
  transpose_cast_b<<<dim3(256, 64, 4), tb, 0, stream>>>(wk1, wk3, wv1, wv3, w4T,
                                                        2048, 8192, 16777216);
  transpose_cast_b<<<dim3(32, 256, 2), tb, 0, stream>>>(wk2, wv2, wk2, wv2, w2T,
                                                        8192, 1024, 8388608);
  transpose_cast_b<<<dim3(64, 64, 2), tb, 0, stream>>>(wq, wo, wq, wo, wqoT,
                                                       2048, 2048, 4194304);

  // q projection: split-K z=2 -> partQO, then reduce (+rope+scale) -> qb
  gemm256<float><<<dim3(128, 2), 512, 0, stream>>>(
      xb, wqT, partQO, 1024, 2048, 2048, 2048, 8, 128, 1024, 1024, 8388608);
  reduce_q<<<16384, 256, 0, stream>>>(partQO, qb, fc, fs);

  // k gates (batched z=2) -> h1,h3; silu; k2 split-K z=4 -> part67; reduce
  gemm256<ushort_t><<<dim3(512, 2), 512, 0, stream>>>(
      xb, wk1T, h1, 2048, 2048, 2048, 8192, 32, 512, 0, 16777216, 33554432);
  silu_mul<<<16384, 256, 0, stream>>>(h1, h1 + 33554432);
  gemm256<float><<<dim3(64, 4), 512, 0, stream>>>(
      h1, wk2T, part67, 2048, 8192, 8192, 1024, 4, 64, 2048, 2048, 4194304);
  reduce_k<<<8192, 256, 0, stream>>>(part67, kb, okeys, fc, fs);

  // v gates -> h1,h3; silu; v2 split-K z=4 -> part67; reduce (+transpose)
  gemm256<ushort_t><<<dim3(512, 2), 512, 0, stream>>>(
      xb, wv1T, h1, 2048, 2048, 2048, 8192, 32, 512, 0, 16777216, 33554432);
  silu_mul<<<16384, 256, 0, stream>>>(h1, h1 + 33554432);
  gemm256<float><<<dim3(64, 4), 512, 0, stream>>>(
      h1, wv2T, part67, 2048, 8192, 8192, 1024, 4, 64, 2048, 2048, 4194304);
  reduce_v<<<dim3(64, 4, 16), tb, 0, stream>>>(part67, ovals, vbT);

  // fused flash attention
  flash_attn<<<dim3(8, 32), 256, 0, stream>>>(qb, kb, vbT, ob);

  // output projection: split-K z=2 -> partQO, reduce -> outp
  gemm256<float><<<dim3(128, 2), 512, 0, stream>>>(
      ob, woT, partQO, 1024, 2048, 2048, 2048, 8, 128, 1024, 1024, 8388608);
  reduce_wo<<<8192, 256, 0, stream>>>(partQO, outp);

  (void)in_sizes; (void)n_in; (void)out_size; (void)ws_size;
}